// Round 12
// baseline (204.505 us; speedup 1.0000x reference)
//
#include <hip/hip_runtime.h>
#include <hip/hip_bf16.h>

typedef __hip_bfloat16 bf16;
typedef __attribute__((ext_vector_type(8))) short short8;   // 8 bf16 = 4 VGPRs
typedef __attribute__((ext_vector_type(4))) float f32x4;

#define BATCH 2
#define SEQ   2048
#define HDIM  1024
#define NHEAD 16
#define DHEAD 64
#define MROWS (BATCH*SEQ)   // 4096

// scale folded into Q: (1/sqrt(64)) * log2(e)  -> softmax done in 2^x domain
#define QSCALE 0.18033688f
#define EXP2F(x) __builtin_amdgcn_exp2f(x)

static __device__ __forceinline__ short f2bs(float x) {
    __hip_bfloat16 h = (__hip_bfloat16)x;   // RNE convert
    return *reinterpret_cast<short*>(&h);
}
static __device__ __forceinline__ unsigned int pk2(float a, float b) {
    __hip_bfloat162 h = __float22bfloat162_rn(make_float2(a, b));
    return *reinterpret_cast<unsigned int*>(&h);   // v_cvt_pk; low short = a
}

// async global->LDS, 16B per lane; lane l lands at base + l*16.
static __device__ __forceinline__ void gload16(const void* g, void* l) {
    __builtin_amdgcn_global_load_lds(
        (const __attribute__((address_space(1))) unsigned int*)g,
        (__attribute__((address_space(3))) unsigned int*)l, 16, 0, 0);
}

// ---------------------------------------------------------------------------
// prep1: blocks 0..4095 convert src fp32->bf16 into Sb; blocks 4096..5119
// transpose all four weights: Wq,Wk,Wv into WT rows wsel*1024+n (WT lives in
// d_out scratch, dead until gemm_o overwrites it), Wo into WoT (slot).
// ---------------------------------------------------------------------------
__global__ __launch_bounds__(256) void prep1(const float* __restrict__ src,
        const float* __restrict__ Wq, const float* __restrict__ Wk,
        const float* __restrict__ Wv, const float* __restrict__ Wo,
        short* __restrict__ Sb, short* __restrict__ WT,
        short* __restrict__ WoT)
{
    __shared__ float t[64][65];
    const int bx = blockIdx.x, tid = threadIdx.x;
    if (bx < 4096) {                       // cvt: 4096*256 float4 = 4M elems
        int i = bx * 256 + tid;
        float4 v = ((const float4*)src)[i];
        ushort4 o;
        o.x = (unsigned short)f2bs(v.x);
        o.y = (unsigned short)f2bs(v.y);
        o.z = (unsigned short)f2bs(v.z);
        o.w = (unsigned short)f2bs(v.w);
        ((ushort4*)Sb)[i] = o;
        return;
    }
    const int tb = bx - 4096;              // [0, 1024)
    const int wsel = tb >> 8;              // 0=Wq 1=Wk 2=Wv 3=Wo
    const float* W = (wsel == 0) ? Wq : (wsel == 1) ? Wk : (wsel == 2) ? Wv : Wo;
    short* dst = (wsel < 3) ? WT : WoT;
    const int roff = (wsel < 3) ? wsel * 1024 : 0;
    const int t8 = tb & 255;
    const int n0 = (t8 & 15) * 64, k0 = (t8 >> 4) * 64;
#pragma unroll
    for (int i = 0; i < 16; i++) {
        int idx = tid + i * 256, r = idx >> 6, c = idx & 63;
        t[r][c] = W[(size_t)(k0 + r) * HDIM + n0 + c];
    }
    __syncthreads();
#pragma unroll
    for (int i = 0; i < 16; i++) {
        int idx = tid + i * 256, c = idx >> 6, r = idx & 63;
        dst[(size_t)(roff + n0 + c) * HDIM + k0 + r] = f2bs(t[r][c]);
    }
}

// ---------------------------------------------------------------------------
// Fused Q|K|V GEMM — 256x256, 8 waves, BK=64, DEEP-ISSUE schedule.
// Staging-rate model (R8/R11 + m201): delivered global->LDS bytes/cyc/CU =
// outstanding-loads x 16B / latency. R8's per-phase group issue kept only
// ~2 loads/thread outstanding with 1-2-phase deadlines -> 8.8 B/cyc (vs
// m201's 19). Fix: issue ALL 8 loads of tile t+1 at tile t's p0 (buffer
// legal: buf(t+1) held tile t-1, compute done before this barrier); waits
// become vmcnt(2) at p0 (tile t's g0-g2, ~4-phase flight) and vmcnt(8)
// mid-tile (tile t's g3; the 8 newer stay in flight). Outstanding 8-10,
// deadlines 4-6 phases. ONE barrier per K-tile (publish + WAR-guard).
// Per-thread issue order g0g1g2g3: A chunks (g0,g1), B chunks {0-7,16-23}
// (g2, feeds n-frags 0-3 of each wave), B {8-15,24-31} (g3, n-frags 4-7).
// MFMA per-acc k-order unchanged -> bit-identical output.
// ---------------------------------------------------------------------------
__global__ __launch_bounds__(512, 2) void gemm_qkv(const short* __restrict__ A,
        const short* __restrict__ Bt,
        const float* __restrict__ bq, const float* __restrict__ bk,
        const float* __restrict__ bv,
        short* __restrict__ Qout, short* __restrict__ Kout,
        short* __restrict__ Vtout)
{
    __shared__ short SM[2][32768];   // [buf][A 16384 | B 16384] = 128 KB
    const int tid = threadIdx.x, lane = tid & 63, w = tid >> 6;   // w 0..7
    const int quad = lane >> 4, l15 = lane & 15;
    const int m0 = blockIdx.y * 256, n0 = blockIdx.x * 256;
    const int wr = w >> 1, wc = w & 1;     // 4M x 2N wave grid

    // staging: 64 chunks/K-tile (chunk = 16 rows x 32 k = 1 KB, one gload16
    // per wave); 4 groups x 16 chunks; per wave 2 chunks per group.
    const short* gp[4][2];
    int lo[4][2];
#pragma unroll
    for (int g = 0; g < 4; g++)
#pragma unroll
        for (int i = 0; i < 2; i++) {
            if (g < 2) {
                int u = g * 16 + w * 2 + i;          // A chunk 0..31
                gp[g][i] = A + (size_t)(m0 + (u >> 1) * 16 + l15) * HDIM
                             + (u & 1) * 32 + quad * 8;
                lo[g][i] = u * 512;
            } else {
                int j = w * 2 + i;                   // 0..15
                int v = (g == 2 ? 0 : 8) + j + (j >= 8 ? 8 : 0);  // B chunk
                gp[g][i] = Bt + (size_t)(n0 + (v >> 1) * 16 + l15) * HDIM
                              + (v & 1) * 32 + quad * 8;
                lo[g][i] = 16384 + v * 512;
            }
        }

    f32x4 acc[4][8];
#pragma unroll
    for (int i = 0; i < 4; i++)
#pragma unroll
        for (int j = 0; j < 8; j++) acc[i][j] = (f32x4){0.f, 0.f, 0.f, 0.f};

    // prologue: issue all 8 loads of tile 0 into buf0
#pragma unroll
    for (int g = 0; g < 4; g++)
#pragma unroll
        for (int i = 0; i < 2; i++) { gload16(gp[g][i], &SM[0][lo[g][i]]); gp[g][i] += 64; }

    short8 af[4][2];
    for (int t = 0; t < 16; ++t) {
        const short* Tb = SM[t & 1];
        short* Sn = SM[(t + 1) & 1];

        asm volatile("s_waitcnt vmcnt(2)" ::: "memory");  // tile t g0,g1,g2 in
        __builtin_amdgcn_s_barrier();                     // publish tile t;
                                                          // all waves past t-1
        // ds_reads: all A frags + B n-frags 0..3 (chunks in g2)
#pragma unroll
        for (int mi = 0; mi < 4; mi++)
#pragma unroll
            for (int kh = 0; kh < 2; kh++)
                af[mi][kh] = *(const short8*)
                    &Tb[((wr * 4 + mi) * 2 + kh) * 512 + lane * 8];
        short8 bf01[4][2];
#pragma unroll
        for (int nn = 0; nn < 4; nn++)
#pragma unroll
            for (int kh = 0; kh < 2; kh++)
                bf01[nn][kh] = *(const short8*)
                    &Tb[16384 + ((wc * 8 + nn) * 2 + kh) * 512 + lane * 8];

        if (t < 15) {                    // issue ALL of tile t+1 now
#pragma unroll
            for (int g = 0; g < 4; g++)
#pragma unroll
                for (int i = 0; i < 2; i++) { gload16(gp[g][i], Sn + lo[g][i]); gp[g][i] += 64; }
        }

        __builtin_amdgcn_s_setprio(1);
#pragma unroll
        for (int nn = 0; nn < 4; nn++)
#pragma unroll
            for (int mi = 0; mi < 4; mi++)
#pragma unroll
                for (int kh = 0; kh < 2; kh++)
                    acc[mi][nn] = __builtin_amdgcn_mfma_f32_16x16x32_bf16(
                        af[mi][kh], bf01[nn][kh], acc[mi][nn], 0, 0, 0);
        __builtin_amdgcn_s_setprio(0);

        if (t < 15) asm volatile("s_waitcnt vmcnt(8)" ::: "memory");  // t g3 in
        else        asm volatile("s_waitcnt vmcnt(0)" ::: "memory");

        short8 bf23[4][2];
#pragma unroll
        for (int nn = 0; nn < 4; nn++)
#pragma unroll
            for (int kh = 0; kh < 2; kh++)
                bf23[nn][kh] = *(const short8*)
                    &Tb[16384 + ((wc * 8 + 4 + nn) * 2 + kh) * 512 + lane * 8];

        __builtin_amdgcn_s_setprio(1);
#pragma unroll
        for (int nn = 0; nn < 4; nn++)
#pragma unroll
            for (int mi = 0; mi < 4; mi++)
#pragma unroll
                for (int kh = 0; kh < 2; kh++)
                    acc[mi][4 + nn] = __builtin_amdgcn_mfma_f32_16x16x32_bf16(
                        af[mi][kh], bf23[nn][kh], acc[mi][4 + nn], 0, 0, 0);
        __builtin_amdgcn_s_setprio(0);
    }

    const int region = blockIdx.x >> 2;          // 0=Q, 1=K, 2=V
    if (region < 2) {
        const float* bias = region ? bk : bq;
        const float oscale = region ? 1.0f : QSCALE;
        short* C = region ? Kout : Qout;
#pragma unroll
        for (int mi = 0; mi < 4; mi++) {
            int mB = m0 + wr * 64 + mi * 16 + quad * 4;
#pragma unroll
            for (int ni = 0; ni < 8; ni++) {
                int nl = (n0 + (wc * 8 + ni) * 16 + l15) & 1023;
                float bb = bias[nl];
#pragma unroll
                for (int r = 0; r < 4; r++)
                    C[(size_t)(mB + r) * HDIM + nl] =
                        f2bs((acc[mi][ni][r] + bb) * oscale);
            }
        }
    } else {                                     // V: transposed store
#pragma unroll
        for (int mi = 0; mi < 4; mi++) {
            int mB = m0 + wr * 64 + mi * 16 + quad * 4;
            int bb = mB >> 11, tt = mB & 2047;
#pragma unroll
            for (int ni = 0; ni < 8; ni++) {
                int n = n0 + (wc * 8 + ni) * 16 + l15;   // 2048..3071
                int h = (n >> 6) & 15, d = n & 63;
                float bvv = bv[n & 1023];
                size_t base = ((size_t)((bb * NHEAD + h) * DHEAD + d)) * SEQ + tt;
                ushort4 pk;
                pk.x = (unsigned short)f2bs(acc[mi][ni][0] + bvv);
                pk.y = (unsigned short)f2bs(acc[mi][ni][1] + bvv);
                pk.z = (unsigned short)f2bs(acc[mi][ni][2] + bvv);
                pk.w = (unsigned short)f2bs(acc[mi][ni][3] + bvv);
                *(ushort4*)(Vtout + base) = pk;
            }
        }
    }
}

// ---------------------------------------------------------------------------
// MFMA causal flash attention with SPLIT LONG STRIPS (R11, passed). Frozen.
// ---------------------------------------------------------------------------
__global__ __launch_bounds__(256) void attn_mfma(const short* __restrict__ Qb,
        const short* __restrict__ Kb, const short* __restrict__ Vt,
        short* __restrict__ Ab,
        float* __restrict__ Opart, float* __restrict__ Psum)
{
    __shared__ short SMEM[20992];        // [2][8192] K|V dbuf | Ps 4x1152
    const int tid = threadIdx.x, lane = tid & 63, w = tid >> 6;
    const int quad = lane >> 4, l15 = lane & 15;
    const int L = blockIdx.x;

    const int pair = (L & 7) + 8 * ((L >> 3) & 3);   // 0..31
    const int u = L >> 5;                            // 0..47
    const int b = pair >> 4, head = pair & 15;
    int s, it0, itEnd, half, split;
    if (u < 32) {
        split = 1; s = 31 - (u >> 1); half = u & 1;
        int mid = (s + 2) >> 1;
        it0 = half ? mid : 0;
        itEnd = half ? (s + 1) : mid;
    } else {
        split = 0; s = 47 - u; half = 0; it0 = 0; itEnd = s + 1;
    }
    const int nj = itEnd - it0;

    const short* Kbh = Kb + (size_t)b * SEQ * HDIM + head * DHEAD;
    const short* Vth = Vt + (size_t)(b * NHEAD + head) * DHEAD * SEQ;
    short* Pw = SMEM + 16384 + w * 1152;

    const int qr = s * 64 + w * 16 + l15;

    const short* qptr = Qb + (size_t)(b * SEQ + qr) * HDIM + head * DHEAD + quad * 8;
    short8 bq0 = *(const short8*)qptr;
    short8 bq1 = *(const short8*)(qptr + 32);

    const short* gp[4];
    int stp[4], ldo[4];
#pragma unroll
    for (int i = 0; i < 4; i++) {
        int c8 = w * 4 + i;
        if (c8 < 8) {
            int t = c8 >> 1, h = c8 & 1;
            gp[i] = Kbh + (size_t)(t * 16 + l15) * HDIM + h * 32 + quad * 8;
            stp[i] = 64 * HDIM;
        } else {
            int c = c8 - 8, dt = c >> 1, kh = c & 1;
            gp[i] = Vth + (size_t)(dt * 16 + l15) * SEQ + kh * 32 + quad * 8;
            stp[i] = 64;
        }
        ldo[i] = c8 * 512;
        gp[i] += (size_t)it0 * stp[i];          // start at tile it0
    }

    f32x4 o[4];
#pragma unroll
    for (int dt = 0; dt < 4; dt++) o[dt] = (f32x4){0.f, 0.f, 0.f, 0.f};
    float psum = 0.f;                    // per-lane partial sum of 2^s

#pragma unroll
    for (int i = 0; i < 4; i++) { gload16(gp[i], &SMEM[ldo[i]]); gp[i] += stp[i]; }

    for (int j = 0; j < nj; ++j) {
        const int cur = j & 1;
        short* Ks = &SMEM[cur * 8192];
        short* Vs = Ks + 4096;

        if (j + 1 < nj) {                // prefetch next tile into other buf
            short* nb = &SMEM[(cur ^ 1) * 8192];
#pragma unroll
            for (int i = 0; i < 4; i++) { gload16(gp[i], nb + ldo[i]); gp[i] += stp[i]; }
            asm volatile("s_waitcnt vmcnt(4)" ::: "memory");   // tile(j) landed
        } else {
            asm volatile("s_waitcnt vmcnt(0)" ::: "memory");
        }
        __builtin_amdgcn_s_barrier();

        const int itg = it0 + j;
        const int s0 = itg * 64;
        f32x4 sv[4];
        __builtin_amdgcn_s_setprio(1);
#pragma unroll
        for (int t = 0; t < 4; t++) {
            sv[t] = (f32x4){0.f, 0.f, 0.f, 0.f};
            short8 k0 = *(const short8*)&Ks[(t * 2) * 512 + lane * 8];
            short8 k1 = *(const short8*)&Ks[(t * 2 + 1) * 512 + lane * 8];
            sv[t] = __builtin_amdgcn_mfma_f32_16x16x32_bf16(k0, bq0, sv[t], 0, 0, 0);
            sv[t] = __builtin_amdgcn_mfma_f32_16x16x32_bf16(k1, bq1, sv[t], 0, 0, 0);
        }
        __builtin_amdgcn_s_setprio(0);

        float p[16];
        if (itg == s) {                  // causal mask only on diagonal tile
#pragma unroll
            for (int t = 0; t < 4; t++)
#pragma unroll
                for (int r = 0; r < 4; r++) {
                    int key = s0 + t * 16 + quad * 4 + r;
                    p[t * 4 + r] = (key <= qr) ? EXP2F(sv[t][r]) : 0.f;
                }
        } else {
#pragma unroll
            for (int t = 0; t < 4; t++)
#pragma unroll
                for (int r = 0; r < 4; r++)
                    p[t * 4 + r] = EXP2F(sv[t][r]);
        }
#pragma unroll
        for (int i = 0; i < 16; i++) psum += p[i];

#pragma unroll
        for (int t = 0; t < 4; t++) {
            uint2 u2;
            u2.x = pk2(p[t * 4],     p[t * 4 + 1]);
            u2.y = pk2(p[t * 4 + 2], p[t * 4 + 3]);
            *(uint2*)&Pw[l15 * 72 + t * 16 + quad * 4] = u2;
        }
        short8 bp0 = *(const short8*)&Pw[l15 * 72 + quad * 8];
        short8 bp1 = *(const short8*)&Pw[l15 * 72 + 32 + quad * 8];

        __builtin_amdgcn_s_setprio(1);
#pragma unroll
        for (int dt = 0; dt < 4; dt++) {
            short8 av0 = *(const short8*)&Vs[(dt * 2) * 512 + lane * 8];
            short8 av1 = *(const short8*)&Vs[(dt * 2 + 1) * 512 + lane * 8];
            o[dt] = __builtin_amdgcn_mfma_f32_16x16x32_bf16(av0, bp0, o[dt], 0, 0, 0);
            o[dt] = __builtin_amdgcn_mfma_f32_16x16x32_bf16(av1, bp1, o[dt], 0, 0, 0);
        }
        __builtin_amdgcn_s_setprio(0);
        __builtin_amdgcn_s_barrier();
    }

    float lrow = psum + __shfl_xor(psum, 16);
    lrow += __shfl_xor(lrow, 32);

    if (split) {                         // f32 partials, no normalize
        const int tile = (pair * 16 + (s - 16)) * 2 + half;
        float* Ot = Opart + (size_t)tile * 4096;
        const int rho = w * 16 + l15;
#pragma unroll
        for (int dt = 0; dt < 4; dt++)
            *(f32x4*)&Ot[rho * 64 + dt * 16 + quad * 4] = o[dt];
        if (quad == 0) Psum[tile * 64 + rho] = lrow;
        return;
    }

    const float inv = 1.f / lrow;
    const size_t obase = (size_t)(b * SEQ + qr) * HDIM + head * DHEAD;
#pragma unroll
    for (int dt = 0; dt < 4; dt++) {
        uint2 u2;
        u2.x = pk2(o[dt][0] * inv, o[dt][1] * inv);
        u2.y = pk2(o[dt][2] * inv, o[dt][3] * inv);
        *(uint2*)&Ab[obase + dt * 16 + quad * 4] = u2;
    }
}

// ---------------------------------------------------------------------------
// combine: sum the two halves' O-partials and row-sums, normalize, write
// bf16 into Ab. (R11, passed.) Frozen.
// ---------------------------------------------------------------------------
__global__ __launch_bounds__(256) void combine(const float* __restrict__ Opart,
        const float* __restrict__ Psum, short* __restrict__ Ab)
{
    const int bxx = blockIdx.x;          // 0..511
    const int pair = bxx & 31, sidx = bxx >> 5;   // sidx 0..15 -> s=16+sidx
    const int b = pair >> 4, head = pair & 15;
    const int s = 16 + sidx;
    const int tid = threadIdx.x;
    const int row = tid >> 2, dq = (tid & 3) * 16;

    const size_t t0 = ((size_t)(pair * 16 + sidx) * 2) * 4096;
    const float* O0 = Opart + t0;
    const float* O1 = O0 + 4096;
    const int p0 = (pair * 16 + sidx) * 2 * 64;
    const float inv = 1.f / (Psum[p0 + row] + Psum[p0 + 64 + row]);

    const size_t obase = (size_t)(b * SEQ + s * 64 + row) * HDIM + head * DHEAD + dq;
#pragma unroll
    for (int g = 0; g < 4; g++) {
        float4 a = *(const float4*)&O0[row * 64 + dq + g * 4];
        float4 c = *(const float4*)&O1[row * 64 + dq + g * 4];
        ushort4 pk;
        pk.x = (unsigned short)f2bs((a.x + c.x) * inv);
        pk.y = (unsigned short)f2bs((a.y + c.y) * inv);
        pk.z = (unsigned short)f2bs((a.z + c.z) * inv);
        pk.w = (unsigned short)f2bs((a.w + c.w) * inv);
        *(ushort4*)&Ab[obase + g * 4] = pk;
    }
}

// ---------------------------------------------------------------------------
// O projection — 128x128, 8 waves, BK=64 counted-vmcnt dbuf (R11, passed).
// Frozen.
// ---------------------------------------------------------------------------
__global__ __launch_bounds__(512) void gemm_o(const short* __restrict__ A,
        const short* __restrict__ Bt, const float* __restrict__ bo,
        float* __restrict__ Out)
{
    __shared__ short SM[2 * 16384];  // [buf][As 8192 | Bs 8192] = 64 KB
    const int tid = threadIdx.x, lane = tid & 63, w = tid >> 6;   // 0..7
    const int quad = lane >> 4, l15 = lane & 15;
    const int m0 = blockIdx.y * 128, n0 = blockIdx.x * 128;
    const int wr = w >> 2, wc = w & 3;   // 2M x 4N

    const short* gsrc[4];
    short* ldst[4];
#pragma unroll
    for (int i = 0; i < 4; i++) {
        int c8 = w * 4 + i;
        if (c8 < 16) {
            gsrc[i] = A + (size_t)(m0 + (c8 >> 1) * 16 + l15) * HDIM
                        + (c8 & 1) * 32 + quad * 8;
            ldst[i] = &SM[c8 * 512];
        } else {
            int v = c8 - 16;
            gsrc[i] = Bt + (size_t)(n0 + (v >> 1) * 16 + l15) * HDIM
                         + (v & 1) * 32 + quad * 8;
            ldst[i] = &SM[8192 + v * 512];
        }
    }

    f32x4 acc[4][2];
#pragma unroll
    for (int i = 0; i < 4; i++)
#pragma unroll
        for (int j = 0; j < 2; j++) acc[i][j] = (f32x4){0.f, 0.f, 0.f, 0.f};

#pragma unroll
    for (int i = 0; i < 4; i++) { gload16(gsrc[i], ldst[i]); gsrc[i] += 64; }

    for (int kk = 0; kk < 16; ++kk) {
        const int cur = kk & 1;
        if (kk < 15) {
            const int nb = (cur ^ 1) * 16384;
#pragma unroll
            for (int i = 0; i < 4; i++) { gload16(gsrc[i], ldst[i] + nb); gsrc[i] += 64; }
            asm volatile("s_waitcnt vmcnt(4)" ::: "memory");   // tile(kk) landed
        } else {
            asm volatile("s_waitcnt vmcnt(0)" ::: "memory");
        }
        __builtin_amdgcn_s_barrier();

        const short* Asb = &SM[cur * 16384];
        const short* Bsb = Asb + 8192;
#pragma unroll
        for (int kh = 0; kh < 2; kh++) {
            short8 af[4], bfr[2];
#pragma unroll
            for (int mi = 0; mi < 4; mi++)
                af[mi] = *(const short8*)&Asb[((wr * 4 + mi) * 2 + kh) * 512 + lane * 8];
#pragma unroll
            for (int ni = 0; ni < 2; ni++)
                bfr[ni] = *(const short8*)&Bsb[((wc * 2 + ni) * 2 + kh) * 512 + lane * 8];
#pragma unroll
            for (int mi = 0; mi < 4; mi++)
#pragma unroll
                for (int ni = 0; ni < 2; ni++)
                    acc[mi][ni] = __builtin_amdgcn_mfma_f32_16x16x32_bf16(
                                      af[mi], bfr[ni], acc[mi][ni], 0, 0, 0);
        }
        __builtin_amdgcn_s_barrier();
    }

#pragma unroll
    for (int mi = 0; mi < 4; mi++) {
        int mB = m0 + (wr * 4 + mi) * 16 + quad * 4;
#pragma unroll
        for (int ni = 0; ni < 2; ni++) {
            int n = n0 + (wc * 2 + ni) * 16 + l15;
            float bb = bo[n];
#pragma unroll
            for (int r = 0; r < 4; r++)
                Out[(size_t)(mB + r) * HDIM + n] = acc[mi][ni][r] + bb;
        }
    }
}

// ---------------------------------------------------------------------------
extern "C" void kernel_launch(void* const* d_in, const int* in_sizes, int n_in,
                              void* d_out, int out_size, void* d_ws, size_t ws_size,
                              hipStream_t stream)
{
    const float* src = (const float*)d_in[0];
    const float* Wq = (const float*)d_in[2];
    const float* bq = (const float*)d_in[3];
    const float* Wk = (const float*)d_in[4];
    const float* bk = (const float*)d_in[5];
    const float* Wv = (const float*)d_in[6];
    const float* bv = (const float*)d_in[7];
    const float* Wo = (const float*)d_in[8];
    const float* bo = (const float*)d_in[9];
    float* out = (float*)d_out;

    // ws (34 MB): [Sb 8][Qb 8][Kb 8][Vt 8][WoT slot 2]
    // d_out scratch timeline: WT (qkv weights) -> attn O-partials -> final out.
    // Sb scratch timeline: src bf16 (qkv input) -> attn psum partials.
    short* Sb   = (short*)d_ws;
    short* Qb   = Sb + (size_t)MROWS * HDIM;
    short* Kb   = Qb + (size_t)MROWS * HDIM;
    short* Vt   = Kb + (size_t)MROWS * HDIM;
    short* WoT  = Vt + (size_t)MROWS * HDIM;   // 2 MB slot
    short* WT   = (short*)d_out;               // 6 MB scratch in out buffer
    short* Ab   = Qb;                          // attention output over Q
    float* Opart = (float*)d_out;              // 16.78 MB: 1024 x 64x64 f32
    float* Psum  = (float*)Sb;                 // 256 KB: 1024 x 64 f32

    prep1<<<dim3(4096 + 1024), dim3(256), 0, stream>>>(src, Wq, Wk, Wv, Wo, Sb, WT, WoT);

    gemm_qkv<<<dim3(12, 16), dim3(512), 0, stream>>>(Sb, WT, bq, bk, bv, Qb, Kb, Vt);

    attn_mfma<<<dim3(1536), dim3(256), 0, stream>>>(Qb, Kb, Vt, Ab, Opart, Psum);

    combine<<<dim3(512), dim3(256), 0, stream>>>(Opart, Psum, Ab);

    gemm_o<<<dim3(8, 32), dim3(512), 0, stream>>>(Ab, WoT, bo, out);
}

// Round 13
// 204.253 us; speedup vs baseline: 1.0012x; 1.0012x over previous
//
#include <hip/hip_runtime.h>
#include <hip/hip_bf16.h>

typedef __hip_bfloat16 bf16;
typedef __attribute__((ext_vector_type(8))) short short8;   // 8 bf16 = 4 VGPRs
typedef __attribute__((ext_vector_type(4))) float f32x4;

#define BATCH 2
#define SEQ   2048
#define HDIM  1024
#define NHEAD 16
#define DHEAD 64
#define MROWS (BATCH*SEQ)   // 4096

// scale folded into Q: (1/sqrt(64)) * log2(e)  -> softmax done in 2^x domain
#define QSCALE 0.18033688f
#define EXP2F(x) __builtin_amdgcn_exp2f(x)

static __device__ __forceinline__ short f2bs(float x) {
    __hip_bfloat16 h = (__hip_bfloat16)x;   // RNE convert
    return *reinterpret_cast<short*>(&h);
}
static __device__ __forceinline__ unsigned int pk2(float a, float b) {
    __hip_bfloat162 h = __float22bfloat162_rn(make_float2(a, b));
    return *reinterpret_cast<unsigned int*>(&h);   // v_cvt_pk; low short = a
}

// async global->LDS, 16B per lane; lane l lands at base + l*16.
static __device__ __forceinline__ void gload16(const void* g, void* l) {
    __builtin_amdgcn_global_load_lds(
        (const __attribute__((address_space(1))) unsigned int*)g,
        (__attribute__((address_space(3))) unsigned int*)l, 16, 0, 0);
}

// ---------------------------------------------------------------------------
// prep1: blocks 0..4095 convert src fp32->bf16 into Sb; blocks 4096..5119
// transpose all four weights: Wq,Wk,Wv into WT rows wsel*1024+n (WT lives in
// d_out scratch, dead until gemm_o overwrites it), Wo into WoT (slot).
// ---------------------------------------------------------------------------
__global__ __launch_bounds__(256) void prep1(const float* __restrict__ src,
        const float* __restrict__ Wq, const float* __restrict__ Wk,
        const float* __restrict__ Wv, const float* __restrict__ Wo,
        short* __restrict__ Sb, short* __restrict__ WT,
        short* __restrict__ WoT)
{
    __shared__ float t[64][65];
    const int bx = blockIdx.x, tid = threadIdx.x;
    if (bx < 4096) {                       // cvt: 4096*256 float4 = 4M elems
        int i = bx * 256 + tid;
        float4 v = ((const float4*)src)[i];
        ushort4 o;
        o.x = (unsigned short)f2bs(v.x);
        o.y = (unsigned short)f2bs(v.y);
        o.z = (unsigned short)f2bs(v.z);
        o.w = (unsigned short)f2bs(v.w);
        ((ushort4*)Sb)[i] = o;
        return;
    }
    const int tb = bx - 4096;              // [0, 1024)
    const int wsel = tb >> 8;              // 0=Wq 1=Wk 2=Wv 3=Wo
    const float* W = (wsel == 0) ? Wq : (wsel == 1) ? Wk : (wsel == 2) ? Wv : Wo;
    short* dst = (wsel < 3) ? WT : WoT;
    const int roff = (wsel < 3) ? wsel * 1024 : 0;
    const int t8 = tb & 255;
    const int n0 = (t8 & 15) * 64, k0 = (t8 >> 4) * 64;
#pragma unroll
    for (int i = 0; i < 16; i++) {
        int idx = tid + i * 256, r = idx >> 6, c = idx & 63;
        t[r][c] = W[(size_t)(k0 + r) * HDIM + n0 + c];
    }
    __syncthreads();
#pragma unroll
    for (int i = 0; i < 16; i++) {
        int idx = tid + i * 256, c = idx >> 6, r = idx & 63;
        dst[(size_t)(roff + n0 + c) * HDIM + k0 + r] = f2bs(t[r][c]);
    }
}

// ---------------------------------------------------------------------------
// Fused Q|K|V GEMM — 256(M) x 192(N), grid (16,16) = 256 blocks = EVERY CU
// exactly once. R8-R12 established the per-CU staging rate is pinned
// (~21 KB/us/CU) regardless of schedule micro-structure; the old 256x256
// grid (12,16)=192 left 64 CUs idle. BN=192 makes the tile count match the
// machine. LDS: A 32 KB + B 24 KB per buffer, dbuf = 112 KB (1 block/CU).
// 8 waves (4M x 2N): per-wave acc[4][6], 48 MFMA/K-tile. 56 staging chunks
// = 7 gload16/wave/tile; ONE vmcnt(0)+barrier per K-tile, tile t+1 issued
// after tile t's ds_reads (deep-issue, R12-equivalent). Tiles straddle the
// Q|K|V boundary -> epilogue resolves region per n-frag (rg = n>>10,
// fragment-uniform since 16|1024). MFMA per-acc k-order unchanged ->
// bit-identical output.
// ---------------------------------------------------------------------------
__global__ __launch_bounds__(512, 2) void gemm_qkv(const short* __restrict__ A,
        const short* __restrict__ Bt,
        const float* __restrict__ bq, const float* __restrict__ bk,
        const float* __restrict__ bv,
        short* __restrict__ Qout, short* __restrict__ Kout,
        short* __restrict__ Vtout)
{
    __shared__ short SM[2][28672];   // [buf][A 16384 | B 12288 shorts] = 112 KB
    const int tid = threadIdx.x, lane = tid & 63, w = tid >> 6;   // w 0..7
    const int quad = lane >> 4, l15 = lane & 15;
    const int m0 = blockIdx.y * 256, n0 = blockIdx.x * 192;
    const int wr = w >> 1, wc = w & 1;     // 4M x 2N wave grid

    // staging: 56 chunks/K-tile (chunk = 16 rows x 32 k = 1 KB, one gload16
    // per wave). Unified numbering c: 0..31 = A chunks, 32..55 = B chunks.
    const short* gp[7];
    int lo[7];
#pragma unroll
    for (int i = 0; i < 7; i++) {
        int c = w * 7 + i;
        if (c < 32) {
            gp[i] = A + (size_t)(m0 + (c >> 1) * 16 + l15) * HDIM
                      + (c & 1) * 32 + quad * 8;
            lo[i] = c * 512;
        } else {
            int v = c - 32;                          // 0..23
            gp[i] = Bt + (size_t)(n0 + (v >> 1) * 16 + l15) * HDIM
                       + (v & 1) * 32 + quad * 8;
            lo[i] = 16384 + v * 512;
        }
    }

    f32x4 acc[4][6];
#pragma unroll
    for (int i = 0; i < 4; i++)
#pragma unroll
        for (int j = 0; j < 6; j++) acc[i][j] = (f32x4){0.f, 0.f, 0.f, 0.f};

    // prologue: issue tile 0 into buf0
#pragma unroll
    for (int i = 0; i < 7; i++) { gload16(gp[i], &SM[0][lo[i]]); gp[i] += 64; }

    for (int t = 0; t < 16; ++t) {
        const short* Tb = SM[t & 1];
        short* Sn = SM[(t + 1) & 1];

        asm volatile("s_waitcnt vmcnt(0)" ::: "memory");  // tile t fully in
        __builtin_amdgcn_s_barrier();                     // publish tile t;
                                                          // WAR on buf(t+1)
                                                          // guarded by t-1's
                                                          // pre-MFMA lgkmcnt
        short8 af[4][2], bf[6][2];
#pragma unroll
        for (int mi = 0; mi < 4; mi++)
#pragma unroll
            for (int kh = 0; kh < 2; kh++)
                af[mi][kh] = *(const short8*)
                    &Tb[((wr * 4 + mi) * 2 + kh) * 512 + lane * 8];
#pragma unroll
        for (int nn = 0; nn < 6; nn++)
#pragma unroll
            for (int kh = 0; kh < 2; kh++)
                bf[nn][kh] = *(const short8*)
                    &Tb[16384 + ((wc * 6 + nn) * 2 + kh) * 512 + lane * 8];

        if (t < 15) {                    // deep-issue: all of tile t+1 now
#pragma unroll
            for (int i = 0; i < 7; i++) { gload16(gp[i], Sn + lo[i]); gp[i] += 64; }
        }

        __builtin_amdgcn_s_setprio(1);
#pragma unroll
        for (int nn = 0; nn < 6; nn++)
#pragma unroll
            for (int mi = 0; mi < 4; mi++)
#pragma unroll
                for (int kh = 0; kh < 2; kh++)
                    acc[mi][nn] = __builtin_amdgcn_mfma_f32_16x16x32_bf16(
                        af[mi][kh], bf[nn][kh], acc[mi][nn], 0, 0, 0);
        __builtin_amdgcn_s_setprio(0);
    }

    // epilogue: region per n-fragment (tiles straddle Q|K|V boundaries)
#pragma unroll
    for (int mi = 0; mi < 4; mi++) {
        int mB = m0 + wr * 64 + mi * 16 + quad * 4;
        int bb = mB >> 11, tt = mB & 2047;
#pragma unroll
        for (int ni = 0; ni < 6; ni++) {
            int n = n0 + wc * 96 + ni * 16 + l15;
            int rg = n >> 10, nl = n & 1023;
            if (rg == 0) {
                float bbv = bq[nl];
#pragma unroll
                for (int r = 0; r < 4; r++)
                    Qout[(size_t)(mB + r) * HDIM + nl] =
                        f2bs((acc[mi][ni][r] + bbv) * QSCALE);
            } else if (rg == 1) {
                float bbv = bk[nl];
#pragma unroll
                for (int r = 0; r < 4; r++)
                    Kout[(size_t)(mB + r) * HDIM + nl] =
                        f2bs(acc[mi][ni][r] + bbv);
            } else {                                 // V: transposed store
                float bvv = bv[nl];
                int h = nl >> 6, d = nl & 63;
                size_t base = ((size_t)((bb * NHEAD + h) * DHEAD + d)) * SEQ + tt;
                ushort4 pk;
                pk.x = (unsigned short)f2bs(acc[mi][ni][0] + bvv);
                pk.y = (unsigned short)f2bs(acc[mi][ni][1] + bvv);
                pk.z = (unsigned short)f2bs(acc[mi][ni][2] + bvv);
                pk.w = (unsigned short)f2bs(acc[mi][ni][3] + bvv);
                *(ushort4*)(Vtout + base) = pk;
            }
        }
    }
}

// ---------------------------------------------------------------------------
// MFMA causal flash attention with SPLIT LONG STRIPS (R11, passed). Frozen.
// ---------------------------------------------------------------------------
__global__ __launch_bounds__(256) void attn_mfma(const short* __restrict__ Qb,
        const short* __restrict__ Kb, const short* __restrict__ Vt,
        short* __restrict__ Ab,
        float* __restrict__ Opart, float* __restrict__ Psum)
{
    __shared__ short SMEM[20992];        // [2][8192] K|V dbuf | Ps 4x1152
    const int tid = threadIdx.x, lane = tid & 63, w = tid >> 6;
    const int quad = lane >> 4, l15 = lane & 15;
    const int L = blockIdx.x;

    const int pair = (L & 7) + 8 * ((L >> 3) & 3);   // 0..31
    const int u = L >> 5;                            // 0..47
    const int b = pair >> 4, head = pair & 15;
    int s, it0, itEnd, half, split;
    if (u < 32) {
        split = 1; s = 31 - (u >> 1); half = u & 1;
        int mid = (s + 2) >> 1;
        it0 = half ? mid : 0;
        itEnd = half ? (s + 1) : mid;
    } else {
        split = 0; s = 47 - u; half = 0; it0 = 0; itEnd = s + 1;
    }
    const int nj = itEnd - it0;

    const short* Kbh = Kb + (size_t)b * SEQ * HDIM + head * DHEAD;
    const short* Vth = Vt + (size_t)(b * NHEAD + head) * DHEAD * SEQ;
    short* Pw = SMEM + 16384 + w * 1152;

    const int qr = s * 64 + w * 16 + l15;

    const short* qptr = Qb + (size_t)(b * SEQ + qr) * HDIM + head * DHEAD + quad * 8;
    short8 bq0 = *(const short8*)qptr;
    short8 bq1 = *(const short8*)(qptr + 32);

    const short* gp[4];
    int stp[4], ldo[4];
#pragma unroll
    for (int i = 0; i < 4; i++) {
        int c8 = w * 4 + i;
        if (c8 < 8) {
            int t = c8 >> 1, h = c8 & 1;
            gp[i] = Kbh + (size_t)(t * 16 + l15) * HDIM + h * 32 + quad * 8;
            stp[i] = 64 * HDIM;
        } else {
            int c = c8 - 8, dt = c >> 1, kh = c & 1;
            gp[i] = Vth + (size_t)(dt * 16 + l15) * SEQ + kh * 32 + quad * 8;
            stp[i] = 64;
        }
        ldo[i] = c8 * 512;
        gp[i] += (size_t)it0 * stp[i];          // start at tile it0
    }

    f32x4 o[4];
#pragma unroll
    for (int dt = 0; dt < 4; dt++) o[dt] = (f32x4){0.f, 0.f, 0.f, 0.f};
    float psum = 0.f;                    // per-lane partial sum of 2^s

#pragma unroll
    for (int i = 0; i < 4; i++) { gload16(gp[i], &SMEM[ldo[i]]); gp[i] += stp[i]; }

    for (int j = 0; j < nj; ++j) {
        const int cur = j & 1;
        short* Ks = &SMEM[cur * 8192];
        short* Vs = Ks + 4096;

        if (j + 1 < nj) {                // prefetch next tile into other buf
            short* nb = &SMEM[(cur ^ 1) * 8192];
#pragma unroll
            for (int i = 0; i < 4; i++) { gload16(gp[i], nb + ldo[i]); gp[i] += stp[i]; }
            asm volatile("s_waitcnt vmcnt(4)" ::: "memory");   // tile(j) landed
        } else {
            asm volatile("s_waitcnt vmcnt(0)" ::: "memory");
        }
        __builtin_amdgcn_s_barrier();

        const int itg = it0 + j;
        const int s0 = itg * 64;
        f32x4 sv[4];
        __builtin_amdgcn_s_setprio(1);
#pragma unroll
        for (int t = 0; t < 4; t++) {
            sv[t] = (f32x4){0.f, 0.f, 0.f, 0.f};
            short8 k0 = *(const short8*)&Ks[(t * 2) * 512 + lane * 8];
            short8 k1 = *(const short8*)&Ks[(t * 2 + 1) * 512 + lane * 8];
            sv[t] = __builtin_amdgcn_mfma_f32_16x16x32_bf16(k0, bq0, sv[t], 0, 0, 0);
            sv[t] = __builtin_amdgcn_mfma_f32_16x16x32_bf16(k1, bq1, sv[t], 0, 0, 0);
        }
        __builtin_amdgcn_s_setprio(0);

        float p[16];
        if (itg == s) {                  // causal mask only on diagonal tile
#pragma unroll
            for (int t = 0; t < 4; t++)
#pragma unroll
                for (int r = 0; r < 4; r++) {
                    int key = s0 + t * 16 + quad * 4 + r;
                    p[t * 4 + r] = (key <= qr) ? EXP2F(sv[t][r]) : 0.f;
                }
        } else {
#pragma unroll
            for (int t = 0; t < 4; t++)
#pragma unroll
                for (int r = 0; r < 4; r++)
                    p[t * 4 + r] = EXP2F(sv[t][r]);
        }
#pragma unroll
        for (int i = 0; i < 16; i++) psum += p[i];

#pragma unroll
        for (int t = 0; t < 4; t++) {
            uint2 u2;
            u2.x = pk2(p[t * 4],     p[t * 4 + 1]);
            u2.y = pk2(p[t * 4 + 2], p[t * 4 + 3]);
            *(uint2*)&Pw[l15 * 72 + t * 16 + quad * 4] = u2;
        }
        short8 bp0 = *(const short8*)&Pw[l15 * 72 + quad * 8];
        short8 bp1 = *(const short8*)&Pw[l15 * 72 + 32 + quad * 8];

        __builtin_amdgcn_s_setprio(1);
#pragma unroll
        for (int dt = 0; dt < 4; dt++) {
            short8 av0 = *(const short8*)&Vs[(dt * 2) * 512 + lane * 8];
            short8 av1 = *(const short8*)&Vs[(dt * 2 + 1) * 512 + lane * 8];
            o[dt] = __builtin_amdgcn_mfma_f32_16x16x32_bf16(av0, bp0, o[dt], 0, 0, 0);
            o[dt] = __builtin_amdgcn_mfma_f32_16x16x32_bf16(av1, bp1, o[dt], 0, 0, 0);
        }
        __builtin_amdgcn_s_setprio(0);
        __builtin_amdgcn_s_barrier();
    }

    float lrow = psum + __shfl_xor(psum, 16);
    lrow += __shfl_xor(lrow, 32);

    if (split) {                         // f32 partials, no normalize
        const int tile = (pair * 16 + (s - 16)) * 2 + half;
        float* Ot = Opart + (size_t)tile * 4096;
        const int rho = w * 16 + l15;
#pragma unroll
        for (int dt = 0; dt < 4; dt++)
            *(f32x4*)&Ot[rho * 64 + dt * 16 + quad * 4] = o[dt];
        if (quad == 0) Psum[tile * 64 + rho] = lrow;
        return;
    }

    const float inv = 1.f / lrow;
    const size_t obase = (size_t)(b * SEQ + qr) * HDIM + head * DHEAD;
#pragma unroll
    for (int dt = 0; dt < 4; dt++) {
        uint2 u2;
        u2.x = pk2(o[dt][0] * inv, o[dt][1] * inv);
        u2.y = pk2(o[dt][2] * inv, o[dt][3] * inv);
        *(uint2*)&Ab[obase + dt * 16 + quad * 4] = u2;
    }
}

// ---------------------------------------------------------------------------
// combine: sum the two halves' O-partials and row-sums, normalize, write
// bf16 into Ab. (R11, passed.) Frozen.
// ---------------------------------------------------------------------------
__global__ __launch_bounds__(256) void combine(const float* __restrict__ Opart,
        const float* __restrict__ Psum, short* __restrict__ Ab)
{
    const int bxx = blockIdx.x;          // 0..511
    const int pair = bxx & 31, sidx = bxx >> 5;   // sidx 0..15 -> s=16+sidx
    const int b = pair >> 4, head = pair & 15;
    const int s = 16 + sidx;
    const int tid = threadIdx.x;
    const int row = tid >> 2, dq = (tid & 3) * 16;

    const size_t t0 = ((size_t)(pair * 16 + sidx) * 2) * 4096;
    const float* O0 = Opart + t0;
    const float* O1 = O0 + 4096;
    const int p0 = (pair * 16 + sidx) * 2 * 64;
    const float inv = 1.f / (Psum[p0 + row] + Psum[p0 + 64 + row]);

    const size_t obase = (size_t)(b * SEQ + s * 64 + row) * HDIM + head * DHEAD + dq;
#pragma unroll
    for (int g = 0; g < 4; g++) {
        float4 a = *(const float4*)&O0[row * 64 + dq + g * 4];
        float4 c = *(const float4*)&O1[row * 64 + dq + g * 4];
        ushort4 pk;
        pk.x = (unsigned short)f2bs((a.x + c.x) * inv);
        pk.y = (unsigned short)f2bs((a.y + c.y) * inv);
        pk.z = (unsigned short)f2bs((a.z + c.z) * inv);
        pk.w = (unsigned short)f2bs((a.w + c.w) * inv);
        *(ushort4*)&Ab[obase + g * 4] = pk;
    }
}

// ---------------------------------------------------------------------------
// O projection — 128x128, 8 waves, BK=64 counted-vmcnt dbuf (R11, passed).
// Frozen.
// ---------------------------------------------------------------------------
__global__ __launch_bounds__(512) void gemm_o(const short* __restrict__ A,
        const short* __restrict__ Bt, const float* __restrict__ bo,
        float* __restrict__ Out)
{
    __shared__ short SM[2 * 16384];  // [buf][As 8192 | Bs 8192] = 64 KB
    const int tid = threadIdx.x, lane = tid & 63, w = tid >> 6;   // 0..7
    const int quad = lane >> 4, l15 = lane & 15;
    const int m0 = blockIdx.y * 128, n0 = blockIdx.x * 128;
    const int wr = w >> 2, wc = w & 3;   // 2M x 4N

    const short* gsrc[4];
    short* ldst[4];
#pragma unroll
    for (int i = 0; i < 4; i++) {
        int c8 = w * 4 + i;
        if (c8 < 16) {
            gsrc[i] = A + (size_t)(m0 + (c8 >> 1) * 16 + l15) * HDIM
                        + (c8 & 1) * 32 + quad * 8;
            ldst[i] = &SM[c8 * 512];
        } else {
            int v = c8 - 16;
            gsrc[i] = Bt + (size_t)(n0 + (v >> 1) * 16 + l15) * HDIM
                         + (v & 1) * 32 + quad * 8;
            ldst[i] = &SM[8192 + v * 512];
        }
    }

    f32x4 acc[4][2];
#pragma unroll
    for (int i = 0; i < 4; i++)
#pragma unroll
        for (int j = 0; j < 2; j++) acc[i][j] = (f32x4){0.f, 0.f, 0.f, 0.f};

#pragma unroll
    for (int i = 0; i < 4; i++) { gload16(gsrc[i], ldst[i]); gsrc[i] += 64; }

    for (int kk = 0; kk < 16; ++kk) {
        const int cur = kk & 1;
        if (kk < 15) {
            const int nb = (cur ^ 1) * 16384;
#pragma unroll
            for (int i = 0; i < 4; i++) { gload16(gsrc[i], ldst[i] + nb); gsrc[i] += 64; }
            asm volatile("s_waitcnt vmcnt(4)" ::: "memory");   // tile(kk) landed
        } else {
            asm volatile("s_waitcnt vmcnt(0)" ::: "memory");
        }
        __builtin_amdgcn_s_barrier();

        const short* Asb = &SM[cur * 16384];
        const short* Bsb = Asb + 8192;
#pragma unroll
        for (int kh = 0; kh < 2; kh++) {
            short8 af[4], bfr[2];
#pragma unroll
            for (int mi = 0; mi < 4; mi++)
                af[mi] = *(const short8*)&Asb[((wr * 4 + mi) * 2 + kh) * 512 + lane * 8];
#pragma unroll
            for (int ni = 0; ni < 2; ni++)
                bfr[ni] = *(const short8*)&Bsb[((wc * 2 + ni) * 2 + kh) * 512 + lane * 8];
#pragma unroll
            for (int mi = 0; mi < 4; mi++)
#pragma unroll
                for (int ni = 0; ni < 2; ni++)
                    acc[mi][ni] = __builtin_amdgcn_mfma_f32_16x16x32_bf16(
                                      af[mi], bfr[ni], acc[mi][ni], 0, 0, 0);
        }
        __builtin_amdgcn_s_barrier();
    }

#pragma unroll
    for (int mi = 0; mi < 4; mi++) {
        int mB = m0 + (wr * 4 + mi) * 16 + quad * 4;
#pragma unroll
        for (int ni = 0; ni < 2; ni++) {
            int n = n0 + (wc * 2 + ni) * 16 + l15;
            float bb = bo[n];
#pragma unroll
            for (int r = 0; r < 4; r++)
                Out[(size_t)(mB + r) * HDIM + n] = acc[mi][ni][r] + bb;
        }
    }
}

// ---------------------------------------------------------------------------
extern "C" void kernel_launch(void* const* d_in, const int* in_sizes, int n_in,
                              void* d_out, int out_size, void* d_ws, size_t ws_size,
                              hipStream_t stream)
{
    const float* src = (const float*)d_in[0];
    const float* Wq = (const float*)d_in[2];
    const float* bq = (const float*)d_in[3];
    const float* Wk = (const float*)d_in[4];
    const float* bk = (const float*)d_in[5];
    const float* Wv = (const float*)d_in[6];
    const float* bv = (const float*)d_in[7];
    const float* Wo = (const float*)d_in[8];
    const float* bo = (const float*)d_in[9];
    float* out = (float*)d_out;

    // ws (34 MB): [Sb 8][Qb 8][Kb 8][Vt 8][WoT slot 2]
    // d_out scratch timeline: WT (qkv weights) -> attn O-partials -> final out.
    // Sb scratch timeline: src bf16 (qkv input) -> attn psum partials.
    short* Sb   = (short*)d_ws;
    short* Qb   = Sb + (size_t)MROWS * HDIM;
    short* Kb   = Qb + (size_t)MROWS * HDIM;
    short* Vt   = Kb + (size_t)MROWS * HDIM;
    short* WoT  = Vt + (size_t)MROWS * HDIM;   // 2 MB slot
    short* WT   = (short*)d_out;               // 6 MB scratch in out buffer
    short* Ab   = Qb;                          // attention output over Q
    float* Opart = (float*)d_out;              // 16.78 MB: 1024 x 64x64 f32
    float* Psum  = (float*)Sb;                 // 256 KB: 1024 x 64 f32

    prep1<<<dim3(4096 + 1024), dim3(256), 0, stream>>>(src, Wq, Wk, Wv, Wo, Sb, WT, WoT);

    gemm_qkv<<<dim3(16, 16), dim3(512), 0, stream>>>(Sb, WT, bq, bk, bv, Qb, Kb, Vt);

    attn_mfma<<<dim3(1536), dim3(256), 0, stream>>>(Qb, Kb, Vt, Ab, Opart, Psum);

    combine<<<dim3(512), dim3(256), 0, stream>>>(Opart, Psum, Ab);

    gemm_o<<<dim3(8, 32), dim3(512), 0, stream>>>(Ab, WoT, bo, out);
}

// Round 14
// 195.219 us; speedup vs baseline: 1.0476x; 1.0463x over previous
//
#include <hip/hip_runtime.h>
#include <hip/hip_bf16.h>

typedef __hip_bfloat16 bf16;
typedef __attribute__((ext_vector_type(8))) short short8;   // 8 bf16 = 4 VGPRs
typedef __attribute__((ext_vector_type(4))) float f32x4;

#define BATCH 2
#define SEQ   2048
#define HDIM  1024
#define NHEAD 16
#define DHEAD 64
#define MROWS (BATCH*SEQ)   // 4096

// scale folded into Q: (1/sqrt(64)) * log2(e)  -> softmax done in 2^x domain
#define QSCALE 0.18033688f
#define EXP2F(x) __builtin_amdgcn_exp2f(x)

static __device__ __forceinline__ short f2bs(float x) {
    __hip_bfloat16 h = (__hip_bfloat16)x;   // RNE convert
    return *reinterpret_cast<short*>(&h);
}
static __device__ __forceinline__ unsigned int pk2(float a, float b) {
    __hip_bfloat162 h = __float22bfloat162_rn(make_float2(a, b));
    return *reinterpret_cast<unsigned int*>(&h);   // v_cvt_pk; low short = a
}

// async global->LDS, 16B per lane; lane l lands at base + l*16.
static __device__ __forceinline__ void gload16(const void* g, void* l) {
    __builtin_amdgcn_global_load_lds(
        (const __attribute__((address_space(1))) unsigned int*)g,
        (__attribute__((address_space(3))) unsigned int*)l, 16, 0, 0);
}

// ---------------------------------------------------------------------------
// prep1: blocks 0..4095 convert src fp32->bf16 into Sb; blocks 4096..5119
// transpose all four weights: Wq,Wk,Wv into WT rows wsel*1024+n (WT lives in
// d_out scratch, dead until gemm_o overwrites it), Wo into WoT (slot).
// ---------------------------------------------------------------------------
__global__ __launch_bounds__(256) void prep1(const float* __restrict__ src,
        const float* __restrict__ Wq, const float* __restrict__ Wk,
        const float* __restrict__ Wv, const float* __restrict__ Wo,
        short* __restrict__ Sb, short* __restrict__ WT,
        short* __restrict__ WoT)
{
    __shared__ float t[64][65];
    const int bx = blockIdx.x, tid = threadIdx.x;
    if (bx < 4096) {                       // cvt: 4096*256 float4 = 4M elems
        int i = bx * 256 + tid;
        float4 v = ((const float4*)src)[i];
        ushort4 o;
        o.x = (unsigned short)f2bs(v.x);
        o.y = (unsigned short)f2bs(v.y);
        o.z = (unsigned short)f2bs(v.z);
        o.w = (unsigned short)f2bs(v.w);
        ((ushort4*)Sb)[i] = o;
        return;
    }
    const int tb = bx - 4096;              // [0, 1024)
    const int wsel = tb >> 8;              // 0=Wq 1=Wk 2=Wv 3=Wo
    const float* W = (wsel == 0) ? Wq : (wsel == 1) ? Wk : (wsel == 2) ? Wv : Wo;
    short* dst = (wsel < 3) ? WT : WoT;
    const int roff = (wsel < 3) ? wsel * 1024 : 0;
    const int t8 = tb & 255;
    const int n0 = (t8 & 15) * 64, k0 = (t8 >> 4) * 64;
#pragma unroll
    for (int i = 0; i < 16; i++) {
        int idx = tid + i * 256, r = idx >> 6, c = idx & 63;
        t[r][c] = W[(size_t)(k0 + r) * HDIM + n0 + c];
    }
    __syncthreads();
#pragma unroll
    for (int i = 0; i < 16; i++) {
        int idx = tid + i * 256, c = idx >> 6, r = idx & 63;
        dst[(size_t)(roff + n0 + c) * HDIM + k0 + r] = f2bs(t[r][c]);
    }
}

// ---------------------------------------------------------------------------
// Fused Q|K|V GEMM — 8-phase 256x256 DEEP-ISSUE (R12, best measured 47.9us).
// Reverted verbatim; R13's BN=192 retile regressed (vmcnt(0) drain exposed
// latency; counted-wait structure > CU coverage).
// ---------------------------------------------------------------------------
__global__ __launch_bounds__(512, 2) void gemm_qkv(const short* __restrict__ A,
        const short* __restrict__ Bt,
        const float* __restrict__ bq, const float* __restrict__ bk,
        const float* __restrict__ bv,
        short* __restrict__ Qout, short* __restrict__ Kout,
        short* __restrict__ Vtout)
{
    __shared__ short SM[2][32768];   // [buf][A 16384 | B 16384] = 128 KB
    const int tid = threadIdx.x, lane = tid & 63, w = tid >> 6;   // w 0..7
    const int quad = lane >> 4, l15 = lane & 15;
    const int m0 = blockIdx.y * 256, n0 = blockIdx.x * 256;
    const int wr = w >> 1, wc = w & 1;     // 4M x 2N wave grid

    const short* gp[4][2];
    int lo[4][2];
#pragma unroll
    for (int g = 0; g < 4; g++)
#pragma unroll
        for (int i = 0; i < 2; i++) {
            if (g < 2) {
                int u = g * 16 + w * 2 + i;          // A chunk 0..31
                gp[g][i] = A + (size_t)(m0 + (u >> 1) * 16 + l15) * HDIM
                             + (u & 1) * 32 + quad * 8;
                lo[g][i] = u * 512;
            } else {
                int j = w * 2 + i;                   // 0..15
                int v = (g == 2 ? 0 : 8) + j + (j >= 8 ? 8 : 0);  // B chunk
                gp[g][i] = Bt + (size_t)(n0 + (v >> 1) * 16 + l15) * HDIM
                              + (v & 1) * 32 + quad * 8;
                lo[g][i] = 16384 + v * 512;
            }
        }

    f32x4 acc[4][8];
#pragma unroll
    for (int i = 0; i < 4; i++)
#pragma unroll
        for (int j = 0; j < 8; j++) acc[i][j] = (f32x4){0.f, 0.f, 0.f, 0.f};

    // prologue: issue all 8 loads of tile 0 into buf0
#pragma unroll
    for (int g = 0; g < 4; g++)
#pragma unroll
        for (int i = 0; i < 2; i++) { gload16(gp[g][i], &SM[0][lo[g][i]]); gp[g][i] += 64; }

    short8 af[4][2];
    for (int t = 0; t < 16; ++t) {
        const short* Tb = SM[t & 1];
        short* Sn = SM[(t + 1) & 1];

        asm volatile("s_waitcnt vmcnt(2)" ::: "memory");  // tile t g0,g1,g2 in
        __builtin_amdgcn_s_barrier();                     // publish tile t
#pragma unroll
        for (int mi = 0; mi < 4; mi++)
#pragma unroll
            for (int kh = 0; kh < 2; kh++)
                af[mi][kh] = *(const short8*)
                    &Tb[((wr * 4 + mi) * 2 + kh) * 512 + lane * 8];
        short8 bf01[4][2];
#pragma unroll
        for (int nn = 0; nn < 4; nn++)
#pragma unroll
            for (int kh = 0; kh < 2; kh++)
                bf01[nn][kh] = *(const short8*)
                    &Tb[16384 + ((wc * 8 + nn) * 2 + kh) * 512 + lane * 8];

        if (t < 15) {                    // issue ALL of tile t+1 now
#pragma unroll
            for (int g = 0; g < 4; g++)
#pragma unroll
                for (int i = 0; i < 2; i++) { gload16(gp[g][i], Sn + lo[g][i]); gp[g][i] += 64; }
        }

        __builtin_amdgcn_s_setprio(1);
#pragma unroll
        for (int nn = 0; nn < 4; nn++)
#pragma unroll
            for (int mi = 0; mi < 4; mi++)
#pragma unroll
                for (int kh = 0; kh < 2; kh++)
                    acc[mi][nn] = __builtin_amdgcn_mfma_f32_16x16x32_bf16(
                        af[mi][kh], bf01[nn][kh], acc[mi][nn], 0, 0, 0);
        __builtin_amdgcn_s_setprio(0);

        if (t < 15) asm volatile("s_waitcnt vmcnt(8)" ::: "memory");  // t g3 in
        else        asm volatile("s_waitcnt vmcnt(0)" ::: "memory");

        short8 bf23[4][2];
#pragma unroll
        for (int nn = 0; nn < 4; nn++)
#pragma unroll
            for (int kh = 0; kh < 2; kh++)
                bf23[nn][kh] = *(const short8*)
                    &Tb[16384 + ((wc * 8 + 4 + nn) * 2 + kh) * 512 + lane * 8];

        __builtin_amdgcn_s_setprio(1);
#pragma unroll
        for (int nn = 0; nn < 4; nn++)
#pragma unroll
            for (int mi = 0; mi < 4; mi++)
#pragma unroll
                for (int kh = 0; kh < 2; kh++)
                    acc[mi][4 + nn] = __builtin_amdgcn_mfma_f32_16x16x32_bf16(
                        af[mi][kh], bf23[nn][kh], acc[mi][4 + nn], 0, 0, 0);
        __builtin_amdgcn_s_setprio(0);
    }

    const int region = blockIdx.x >> 2;          // 0=Q, 1=K, 2=V
    if (region < 2) {
        const float* bias = region ? bk : bq;
        const float oscale = region ? 1.0f : QSCALE;
        short* C = region ? Kout : Qout;
#pragma unroll
        for (int mi = 0; mi < 4; mi++) {
            int mB = m0 + wr * 64 + mi * 16 + quad * 4;
#pragma unroll
            for (int ni = 0; ni < 8; ni++) {
                int nl = (n0 + (wc * 8 + ni) * 16 + l15) & 1023;
                float bb = bias[nl];
#pragma unroll
                for (int r = 0; r < 4; r++)
                    C[(size_t)(mB + r) * HDIM + nl] =
                        f2bs((acc[mi][ni][r] + bb) * oscale);
            }
        }
    } else {                                     // V: transposed store
#pragma unroll
        for (int mi = 0; mi < 4; mi++) {
            int mB = m0 + wr * 64 + mi * 16 + quad * 4;
            int bb = mB >> 11, tt = mB & 2047;
#pragma unroll
            for (int ni = 0; ni < 8; ni++) {
                int n = n0 + (wc * 8 + ni) * 16 + l15;   // 2048..3071
                int h = (n >> 6) & 15, d = n & 63;
                float bvv = bv[n & 1023];
                size_t base = ((size_t)((bb * NHEAD + h) * DHEAD + d)) * SEQ + tt;
                ushort4 pk;
                pk.x = (unsigned short)f2bs(acc[mi][ni][0] + bvv);
                pk.y = (unsigned short)f2bs(acc[mi][ni][1] + bvv);
                pk.z = (unsigned short)f2bs(acc[mi][ni][2] + bvv);
                pk.w = (unsigned short)f2bs(acc[mi][ni][3] + bvv);
                *(ushort4*)(Vtout + base) = pk;
            }
        }
    }
}

// ---------------------------------------------------------------------------
// MFMA causal flash attention — 128 Q-ROWS PER BLOCK (8 waves; strips 2s and
// 2s+1 SHARE one K/V staging stream). Staging-rate model: attn cost ≈ staged
// bytes / (21 KB/us/CU); doubling rows/block halves staged bytes per unit
// work (16896 -> 8704 block-iters x 16 KB). Per-wave code identical to the
// proven 4-wave version (each wave owns 16 q-rows); per-wave strip s_w =
// 2*sblk + (w>>2); causal mask applied when itg >= s_w (for itg > s_w all
// p=0 automatically -> uniform barriers, lower strip idles 1 tile).
// Blocks own full rows -> direct Ab write (combine kernel deleted).
// LDS: 2 x 16 KB K|V dbuf + 18 KB P = 50 KB -> 3 blocks/CU. 512 blocks,
// heavy-first (sblk = 15 - L>>5), XCD affinity per (b,head).
// ---------------------------------------------------------------------------
__global__ __launch_bounds__(512) void attn_mfma(const short* __restrict__ Qb,
        const short* __restrict__ Kb, const short* __restrict__ Vt,
        short* __restrict__ Ab)
{
    __shared__ short SMEM[25600];        // [2][8192] K|V dbuf | Ps 8x1152
    const int tid = threadIdx.x, lane = tid & 63, w = tid >> 6;   // w 0..7
    const int quad = lane >> 4, l15 = lane & 15;
    const int L = blockIdx.x;

    const int pair = (L & 7) + 8 * ((L >> 3) & 3);   // 0..31
    const int sblk = 15 - (L >> 5);                  // 0..15, heavy first
    const int b = pair >> 4, head = pair & 15;
    const int nj = 2 * sblk + 2;                     // tiles 0..2*sblk+1

    const short* Kbh = Kb + (size_t)b * SEQ * HDIM + head * DHEAD;
    const short* Vth = Vt + (size_t)(b * NHEAD + head) * DHEAD * SEQ;
    short* Pw = SMEM + 16384 + w * 1152;

    const int s_w = 2 * sblk + (w >> 2);             // this wave's strip
    const int qr = sblk * 128 + w * 16 + l15;        // this lane's q-row

    const short* qptr = Qb + (size_t)(b * SEQ + qr) * HDIM + head * DHEAD + quad * 8;
    short8 bq0 = *(const short8*)qptr;
    short8 bq1 = *(const short8*)(qptr + 32);

    // staging: 16 chunks/tile (8 K + 8 V), 2 per wave
    const short* gp[2];
    int stp[2], ldo[2];
#pragma unroll
    for (int i = 0; i < 2; i++) {
        int c8 = w * 2 + i;
        if (c8 < 8) {
            int t = c8 >> 1, h = c8 & 1;
            gp[i] = Kbh + (size_t)(t * 16 + l15) * HDIM + h * 32 + quad * 8;
            stp[i] = 64 * HDIM;
        } else {
            int c = c8 - 8, dt = c >> 1, kh = c & 1;
            gp[i] = Vth + (size_t)(dt * 16 + l15) * SEQ + kh * 32 + quad * 8;
            stp[i] = 64;
        }
        ldo[i] = c8 * 512;
    }

    f32x4 o[4];
#pragma unroll
    for (int dt = 0; dt < 4; dt++) o[dt] = (f32x4){0.f, 0.f, 0.f, 0.f};
    float psum = 0.f;                    // per-lane partial sum of 2^s

    // prologue: stage tile 0 into buffer 0
#pragma unroll
    for (int i = 0; i < 2; i++) { gload16(gp[i], &SMEM[ldo[i]]); gp[i] += stp[i]; }

    for (int j = 0; j < nj; ++j) {
        const int cur = j & 1;
        short* Ks = &SMEM[cur * 8192];
        short* Vs = Ks + 4096;

        if (j + 1 < nj) {                // prefetch next tile into other buf
            short* nb = &SMEM[(cur ^ 1) * 8192];
#pragma unroll
            for (int i = 0; i < 2; i++) { gload16(gp[i], nb + ldo[i]); gp[i] += stp[i]; }
            asm volatile("s_waitcnt vmcnt(2)" ::: "memory");   // tile(j) landed
        } else {
            asm volatile("s_waitcnt vmcnt(0)" ::: "memory");
        }
        __builtin_amdgcn_s_barrier();    // tile j visible; prev reads done

        const int s0 = j * 64;
        f32x4 sv[4];
        __builtin_amdgcn_s_setprio(1);
#pragma unroll
        for (int t = 0; t < 4; t++) {
            sv[t] = (f32x4){0.f, 0.f, 0.f, 0.f};
            short8 k0 = *(const short8*)&Ks[(t * 2) * 512 + lane * 8];
            short8 k1 = *(const short8*)&Ks[(t * 2 + 1) * 512 + lane * 8];
            sv[t] = __builtin_amdgcn_mfma_f32_16x16x32_bf16(k0, bq0, sv[t], 0, 0, 0);
            sv[t] = __builtin_amdgcn_mfma_f32_16x16x32_bf16(k1, bq1, sv[t], 0, 0, 0);
        }
        __builtin_amdgcn_s_setprio(0);

        float p[16];
        if (j >= s_w) {                  // diagonal or beyond for this wave
#pragma unroll
            for (int t = 0; t < 4; t++)
#pragma unroll
                for (int r = 0; r < 4; r++) {
                    int key = s0 + t * 16 + quad * 4 + r;
                    p[t * 4 + r] = (key <= qr) ? EXP2F(sv[t][r]) : 0.f;
                }
        } else {
#pragma unroll
            for (int t = 0; t < 4; t++)
#pragma unroll
                for (int r = 0; r < 4; r++)
                    p[t * 4 + r] = EXP2F(sv[t][r]);
        }
#pragma unroll
        for (int i = 0; i < 16; i++) psum += p[i];

#pragma unroll
        for (int t = 0; t < 4; t++) {
            uint2 u2;
            u2.x = pk2(p[t * 4],     p[t * 4 + 1]);
            u2.y = pk2(p[t * 4 + 2], p[t * 4 + 3]);
            *(uint2*)&Pw[l15 * 72 + t * 16 + quad * 4] = u2;
        }
        short8 bp0 = *(const short8*)&Pw[l15 * 72 + quad * 8];
        short8 bp1 = *(const short8*)&Pw[l15 * 72 + 32 + quad * 8];

        __builtin_amdgcn_s_setprio(1);
#pragma unroll
        for (int dt = 0; dt < 4; dt++) {
            short8 av0 = *(const short8*)&Vs[(dt * 2) * 512 + lane * 8];
            short8 av1 = *(const short8*)&Vs[(dt * 2 + 1) * 512 + lane * 8];
            o[dt] = __builtin_amdgcn_mfma_f32_16x16x32_bf16(av0, bp0, o[dt], 0, 0, 0);
            o[dt] = __builtin_amdgcn_mfma_f32_16x16x32_bf16(av1, bp1, o[dt], 0, 0, 0);
        }
        __builtin_amdgcn_s_setprio(0);
        __builtin_amdgcn_s_barrier();    // reads of buf(cur) done before
                                         // next iter's prefetch overwrites
    }

    float lrow = psum + __shfl_xor(psum, 16);
    lrow += __shfl_xor(lrow, 32);
    const float inv = 1.f / lrow;

    const size_t obase = (size_t)(b * SEQ + qr) * HDIM + head * DHEAD;
#pragma unroll
    for (int dt = 0; dt < 4; dt++) {
        uint2 u2;
        u2.x = pk2(o[dt][0] * inv, o[dt][1] * inv);
        u2.y = pk2(o[dt][2] * inv, o[dt][3] * inv);
        *(uint2*)&Ab[obase + dt * 16 + quad * 4] = u2;
    }
}

// ---------------------------------------------------------------------------
// O projection — 128x128, 8 waves, BK=64 counted-vmcnt dbuf (R11/R12,
// passed). Frozen.
// ---------------------------------------------------------------------------
__global__ __launch_bounds__(512) void gemm_o(const short* __restrict__ A,
        const short* __restrict__ Bt, const float* __restrict__ bo,
        float* __restrict__ Out)
{
    __shared__ short SM[2 * 16384];  // [buf][As 8192 | Bs 8192] = 64 KB
    const int tid = threadIdx.x, lane = tid & 63, w = tid >> 6;   // 0..7
    const int quad = lane >> 4, l15 = lane & 15;
    const int m0 = blockIdx.y * 128, n0 = blockIdx.x * 128;
    const int wr = w >> 2, wc = w & 3;   // 2M x 4N

    const short* gsrc[4];
    short* ldst[4];
#pragma unroll
    for (int i = 0; i < 4; i++) {
        int c8 = w * 4 + i;
        if (c8 < 16) {
            gsrc[i] = A + (size_t)(m0 + (c8 >> 1) * 16 + l15) * HDIM
                        + (c8 & 1) * 32 + quad * 8;
            ldst[i] = &SM[c8 * 512];
        } else {
            int v = c8 - 16;
            gsrc[i] = Bt + (size_t)(n0 + (v >> 1) * 16 + l15) * HDIM
                         + (v & 1) * 32 + quad * 8;
            ldst[i] = &SM[8192 + v * 512];
        }
    }

    f32x4 acc[4][2];
#pragma unroll
    for (int i = 0; i < 4; i++)
#pragma unroll
        for (int j = 0; j < 2; j++) acc[i][j] = (f32x4){0.f, 0.f, 0.f, 0.f};

#pragma unroll
    for (int i = 0; i < 4; i++) { gload16(gsrc[i], ldst[i]); gsrc[i] += 64; }

    for (int kk = 0; kk < 16; ++kk) {
        const int cur = kk & 1;
        if (kk < 15) {
            const int nb = (cur ^ 1) * 16384;
#pragma unroll
            for (int i = 0; i < 4; i++) { gload16(gsrc[i], ldst[i] + nb); gsrc[i] += 64; }
            asm volatile("s_waitcnt vmcnt(4)" ::: "memory");   // tile(kk) landed
        } else {
            asm volatile("s_waitcnt vmcnt(0)" ::: "memory");
        }
        __builtin_amdgcn_s_barrier();

        const short* Asb = &SM[cur * 16384];
        const short* Bsb = Asb + 8192;
#pragma unroll
        for (int kh = 0; kh < 2; kh++) {
            short8 af[4], bfr[2];
#pragma unroll
            for (int mi = 0; mi < 4; mi++)
                af[mi] = *(const short8*)&Asb[((wr * 4 + mi) * 2 + kh) * 512 + lane * 8];
#pragma unroll
            for (int ni = 0; ni < 2; ni++)
                bfr[ni] = *(const short8*)&Bsb[((wc * 2 + ni) * 2 + kh) * 512 + lane * 8];
#pragma unroll
            for (int mi = 0; mi < 4; mi++)
#pragma unroll
                for (int ni = 0; ni < 2; ni++)
                    acc[mi][ni] = __builtin_amdgcn_mfma_f32_16x16x32_bf16(
                                      af[mi], bfr[ni], acc[mi][ni], 0, 0, 0);
        }
        __builtin_amdgcn_s_barrier();
    }

#pragma unroll
    for (int mi = 0; mi < 4; mi++) {
        int mB = m0 + (wr * 4 + mi) * 16 + quad * 4;
#pragma unroll
        for (int ni = 0; ni < 2; ni++) {
            int n = n0 + (wc * 2 + ni) * 16 + l15;
            float bb = bo[n];
#pragma unroll
            for (int r = 0; r < 4; r++)
                Out[(size_t)(mB + r) * HDIM + n] = acc[mi][ni][r] + bb;
        }
    }
}

// ---------------------------------------------------------------------------
extern "C" void kernel_launch(void* const* d_in, const int* in_sizes, int n_in,
                              void* d_out, int out_size, void* d_ws, size_t ws_size,
                              hipStream_t stream)
{
    const float* src = (const float*)d_in[0];
    const float* Wq = (const float*)d_in[2];
    const float* bq = (const float*)d_in[3];
    const float* Wk = (const float*)d_in[4];
    const float* bk = (const float*)d_in[5];
    const float* Wv = (const float*)d_in[6];
    const float* bv = (const float*)d_in[7];
    const float* Wo = (const float*)d_in[8];
    const float* bo = (const float*)d_in[9];
    float* out = (float*)d_out;

    // ws (34 MB): [Sb 8][Qb 8][Kb 8][Vt 8][WoT slot 2]
    // d_out scratch timeline: WT (qkv weights) -> final out (gemm_o).
    short* Sb   = (short*)d_ws;
    short* Qb   = Sb + (size_t)MROWS * HDIM;
    short* Kb   = Qb + (size_t)MROWS * HDIM;
    short* Vt   = Kb + (size_t)MROWS * HDIM;
    short* WoT  = Vt + (size_t)MROWS * HDIM;   // 2 MB slot
    short* WT   = (short*)d_out;               // 6 MB scratch in out buffer
    short* Ab   = Qb;                          // attention output over Q

    prep1<<<dim3(4096 + 1024), dim3(256), 0, stream>>>(src, Wq, Wk, Wv, Wo, Sb, WT, WoT);

    gemm_qkv<<<dim3(12, 16), dim3(512), 0, stream>>>(Sb, WT, bq, bk, bv, Qb, Kb, Vt);

    attn_mfma<<<dim3(512), dim3(512), 0, stream>>>(Qb, Kb, Vt, Ab);

    gemm_o<<<dim3(8, 32), dim3(512), 0, stream>>>(Ab, WoT, bo, out);
}

// Round 15
// 193.639 us; speedup vs baseline: 1.0561x; 1.0082x over previous
//
#include <hip/hip_runtime.h>
#include <hip/hip_bf16.h>

typedef __hip_bfloat16 bf16;
typedef __attribute__((ext_vector_type(8))) short short8;   // 8 bf16 = 4 VGPRs
typedef __attribute__((ext_vector_type(4))) float f32x4;

#define BATCH 2
#define SEQ   2048
#define HDIM  1024
#define NHEAD 16
#define DHEAD 64
#define MROWS (BATCH*SEQ)   // 4096

// scale folded into Q: (1/sqrt(64)) * log2(e)  -> softmax done in 2^x domain
#define QSCALE 0.18033688f
#define EXP2F(x) __builtin_amdgcn_exp2f(x)

static __device__ __forceinline__ short f2bs(float x) {
    __hip_bfloat16 h = (__hip_bfloat16)x;   // RNE convert
    return *reinterpret_cast<short*>(&h);
}
static __device__ __forceinline__ unsigned int pk2(float a, float b) {
    __hip_bfloat162 h = __float22bfloat162_rn(make_float2(a, b));
    return *reinterpret_cast<unsigned int*>(&h);   // v_cvt_pk; low short = a
}

// async global->LDS, 16B per lane; lane l lands at base + l*16.
static __device__ __forceinline__ void gload16(const void* g, void* l) {
    __builtin_amdgcn_global_load_lds(
        (const __attribute__((address_space(1))) unsigned int*)g,
        (__attribute__((address_space(3))) unsigned int*)l, 16, 0, 0);
}

// ---------------------------------------------------------------------------
// prep1: blocks 0..4095 convert src fp32->bf16 into Sb; blocks 4096..5119
// transpose all four weights: Wq,Wk,Wv into WT rows wsel*1024+n (WT lives in
// d_out scratch, dead until gemm_o overwrites it), Wo into WoT (slot).
// ---------------------------------------------------------------------------
__global__ __launch_bounds__(256) void prep1(const float* __restrict__ src,
        const float* __restrict__ Wq, const float* __restrict__ Wk,
        const float* __restrict__ Wv, const float* __restrict__ Wo,
        short* __restrict__ Sb, short* __restrict__ WT,
        short* __restrict__ WoT)
{
    __shared__ float t[64][65];
    const int bx = blockIdx.x, tid = threadIdx.x;
    if (bx < 4096) {                       // cvt: 4096*256 float4 = 4M elems
        int i = bx * 256 + tid;
        float4 v = ((const float4*)src)[i];
        ushort4 o;
        o.x = (unsigned short)f2bs(v.x);
        o.y = (unsigned short)f2bs(v.y);
        o.z = (unsigned short)f2bs(v.z);
        o.w = (unsigned short)f2bs(v.w);
        ((ushort4*)Sb)[i] = o;
        return;
    }
    const int tb = bx - 4096;              // [0, 1024)
    const int wsel = tb >> 8;              // 0=Wq 1=Wk 2=Wv 3=Wo
    const float* W = (wsel == 0) ? Wq : (wsel == 1) ? Wk : (wsel == 2) ? Wv : Wo;
    short* dst = (wsel < 3) ? WT : WoT;
    const int roff = (wsel < 3) ? wsel * 1024 : 0;
    const int t8 = tb & 255;
    const int n0 = (t8 & 15) * 64, k0 = (t8 >> 4) * 64;
#pragma unroll
    for (int i = 0; i < 16; i++) {
        int idx = tid + i * 256, r = idx >> 6, c = idx & 63;
        t[r][c] = W[(size_t)(k0 + r) * HDIM + n0 + c];
    }
    __syncthreads();
#pragma unroll
    for (int i = 0; i < 16; i++) {
        int idx = tid + i * 256, c = idx >> 6, r = idx & 63;
        dst[(size_t)(roff + n0 + c) * HDIM + k0 + r] = f2bs(t[r][c]);
    }
}

// ---------------------------------------------------------------------------
// Fused Q|K|V GEMM — 8-phase 256x256 DEEP-ISSUE (R12/R14, passed). Frozen.
// ---------------------------------------------------------------------------
__global__ __launch_bounds__(512, 2) void gemm_qkv(const short* __restrict__ A,
        const short* __restrict__ Bt,
        const float* __restrict__ bq, const float* __restrict__ bk,
        const float* __restrict__ bv,
        short* __restrict__ Qout, short* __restrict__ Kout,
        short* __restrict__ Vtout)
{
    __shared__ short SM[2][32768];   // [buf][A 16384 | B 16384] = 128 KB
    const int tid = threadIdx.x, lane = tid & 63, w = tid >> 6;   // w 0..7
    const int quad = lane >> 4, l15 = lane & 15;
    const int m0 = blockIdx.y * 256, n0 = blockIdx.x * 256;
    const int wr = w >> 1, wc = w & 1;     // 4M x 2N wave grid

    const short* gp[4][2];
    int lo[4][2];
#pragma unroll
    for (int g = 0; g < 4; g++)
#pragma unroll
        for (int i = 0; i < 2; i++) {
            if (g < 2) {
                int u = g * 16 + w * 2 + i;          // A chunk 0..31
                gp[g][i] = A + (size_t)(m0 + (u >> 1) * 16 + l15) * HDIM
                             + (u & 1) * 32 + quad * 8;
                lo[g][i] = u * 512;
            } else {
                int j = w * 2 + i;                   // 0..15
                int v = (g == 2 ? 0 : 8) + j + (j >= 8 ? 8 : 0);  // B chunk
                gp[g][i] = Bt + (size_t)(n0 + (v >> 1) * 16 + l15) * HDIM
                              + (v & 1) * 32 + quad * 8;
                lo[g][i] = 16384 + v * 512;
            }
        }

    f32x4 acc[4][8];
#pragma unroll
    for (int i = 0; i < 4; i++)
#pragma unroll
        for (int j = 0; j < 8; j++) acc[i][j] = (f32x4){0.f, 0.f, 0.f, 0.f};

    // prologue: issue all 8 loads of tile 0 into buf0
#pragma unroll
    for (int g = 0; g < 4; g++)
#pragma unroll
        for (int i = 0; i < 2; i++) { gload16(gp[g][i], &SM[0][lo[g][i]]); gp[g][i] += 64; }

    short8 af[4][2];
    for (int t = 0; t < 16; ++t) {
        const short* Tb = SM[t & 1];
        short* Sn = SM[(t + 1) & 1];

        asm volatile("s_waitcnt vmcnt(2)" ::: "memory");  // tile t g0,g1,g2 in
        __builtin_amdgcn_s_barrier();                     // publish tile t
#pragma unroll
        for (int mi = 0; mi < 4; mi++)
#pragma unroll
            for (int kh = 0; kh < 2; kh++)
                af[mi][kh] = *(const short8*)
                    &Tb[((wr * 4 + mi) * 2 + kh) * 512 + lane * 8];
        short8 bf01[4][2];
#pragma unroll
        for (int nn = 0; nn < 4; nn++)
#pragma unroll
            for (int kh = 0; kh < 2; kh++)
                bf01[nn][kh] = *(const short8*)
                    &Tb[16384 + ((wc * 8 + nn) * 2 + kh) * 512 + lane * 8];

        if (t < 15) {                    // issue ALL of tile t+1 now
#pragma unroll
            for (int g = 0; g < 4; g++)
#pragma unroll
                for (int i = 0; i < 2; i++) { gload16(gp[g][i], Sn + lo[g][i]); gp[g][i] += 64; }
        }

        __builtin_amdgcn_s_setprio(1);
#pragma unroll
        for (int nn = 0; nn < 4; nn++)
#pragma unroll
            for (int mi = 0; mi < 4; mi++)
#pragma unroll
                for (int kh = 0; kh < 2; kh++)
                    acc[mi][nn] = __builtin_amdgcn_mfma_f32_16x16x32_bf16(
                        af[mi][kh], bf01[nn][kh], acc[mi][nn], 0, 0, 0);
        __builtin_amdgcn_s_setprio(0);

        if (t < 15) asm volatile("s_waitcnt vmcnt(8)" ::: "memory");  // t g3 in
        else        asm volatile("s_waitcnt vmcnt(0)" ::: "memory");

        short8 bf23[4][2];
#pragma unroll
        for (int nn = 0; nn < 4; nn++)
#pragma unroll
            for (int kh = 0; kh < 2; kh++)
                bf23[nn][kh] = *(const short8*)
                    &Tb[16384 + ((wc * 8 + 4 + nn) * 2 + kh) * 512 + lane * 8];

        __builtin_amdgcn_s_setprio(1);
#pragma unroll
        for (int nn = 0; nn < 4; nn++)
#pragma unroll
            for (int mi = 0; mi < 4; mi++)
#pragma unroll
                for (int kh = 0; kh < 2; kh++)
                    acc[mi][4 + nn] = __builtin_amdgcn_mfma_f32_16x16x32_bf16(
                        af[mi][kh], bf23[nn][kh], acc[mi][4 + nn], 0, 0, 0);
        __builtin_amdgcn_s_setprio(0);
    }

    const int region = blockIdx.x >> 2;          // 0=Q, 1=K, 2=V
    if (region < 2) {
        const float* bias = region ? bk : bq;
        const float oscale = region ? 1.0f : QSCALE;
        short* C = region ? Kout : Qout;
#pragma unroll
        for (int mi = 0; mi < 4; mi++) {
            int mB = m0 + wr * 64 + mi * 16 + quad * 4;
#pragma unroll
            for (int ni = 0; ni < 8; ni++) {
                int nl = (n0 + (wc * 8 + ni) * 16 + l15) & 1023;
                float bb = bias[nl];
#pragma unroll
                for (int r = 0; r < 4; r++)
                    C[(size_t)(mB + r) * HDIM + nl] =
                        f2bs((acc[mi][ni][r] + bb) * oscale);
            }
        }
    } else {                                     // V: transposed store
#pragma unroll
        for (int mi = 0; mi < 4; mi++) {
            int mB = m0 + wr * 64 + mi * 16 + quad * 4;
            int bb = mB >> 11, tt = mB & 2047;
#pragma unroll
            for (int ni = 0; ni < 8; ni++) {
                int n = n0 + (wc * 8 + ni) * 16 + l15;   // 2048..3071
                int h = (n >> 6) & 15, d = n & 63;
                float bvv = bv[n & 1023];
                size_t base = ((size_t)((bb * NHEAD + h) * DHEAD + d)) * SEQ + tt;
                ushort4 pk;
                pk.x = (unsigned short)f2bs(acc[mi][ni][0] + bvv);
                pk.y = (unsigned short)f2bs(acc[mi][ni][1] + bvv);
                pk.z = (unsigned short)f2bs(acc[mi][ni][2] + bvv);
                pk.w = (unsigned short)f2bs(acc[mi][ni][3] + bvv);
                *(ushort4*)(Vtout + base) = pk;
            }
        }
    }
}

// ---------------------------------------------------------------------------
// MFMA causal flash attention — 128 Q-rows/block shared staging (R14) +
// SPLIT LONG STRIPS (R11): the two proven, orthogonal wins combined.
// sblk 0..7 unsplit (2..16 iters, direct Ab write); sblk 8..15 split into
// KV-halves [0,s+1) / [s+1,2s+2) (9..16 iters each) writing additive f32
// partials (fixed-max softmax: O=O0+O1, l=l0+l1) to Opart/Psum scratch.
// 768 blocks = 3/CU exactly; 24 units/pair sorted heavy-first; block-iters
// 8704 (staged bytes = R14); critical path 32 -> 16 iters.
// Per-wave strip s_w = 2*sblk + (w>>2); mask when itg >= s_w.
// LDS: 2 x 8 KB K|V dbuf + 9 KB P = 50 KB (8 waves x 1152 P).
// ---------------------------------------------------------------------------
__global__ __launch_bounds__(512) void attn_mfma(const short* __restrict__ Qb,
        const short* __restrict__ Kb, const short* __restrict__ Vt,
        short* __restrict__ Ab,
        float* __restrict__ Opart, float* __restrict__ Psum)
{
    __shared__ short SMEM[25600];        // [2][8192] K|V dbuf | Ps 8x1152
    const int tid = threadIdx.x, lane = tid & 63, w = tid >> 6;   // w 0..7
    const int quad = lane >> 4, l15 = lane & 15;
    const int L = blockIdx.x;

    // unit table sorted by descending iteration count (heavy first)
    static const signed char S_TAB[24] =
        {15,15, 7,14,14,13,13, 6,12,12,11,11, 5,10,10, 9, 9, 4, 8, 8, 3, 2, 1, 0};
    static const signed char H_TAB[24] =
        { 0, 1,-1, 0, 1, 0, 1,-1, 0, 1, 0, 1,-1, 0, 1, 0, 1,-1, 0, 1,-1,-1,-1,-1};

    const int pair = (L & 7) + 8 * ((L >> 3) & 3);   // 0..31 (XCD affinity)
    const int u = L >> 5;                            // 0..23
    const int b = pair >> 4, head = pair & 15;
    const int sblk = S_TAB[u];
    const int half = H_TAB[u];                       // -1 unsplit, 0/1 halves
    const int it0   = (half == 1) ? (sblk + 1) : 0;
    const int itEnd = (half == 0) ? (sblk + 1) : (2 * sblk + 2);
    const int nj = itEnd - it0;

    const short* Kbh = Kb + (size_t)b * SEQ * HDIM + head * DHEAD;
    const short* Vth = Vt + (size_t)(b * NHEAD + head) * DHEAD * SEQ;
    short* Pw = SMEM + 16384 + w * 1152;

    const int s_w = 2 * sblk + (w >> 2);             // this wave's 64-strip
    const int rho = w * 16 + l15;                    // row within block 0..127
    const int qr = sblk * 128 + rho;                 // this lane's q-row

    const short* qptr = Qb + (size_t)(b * SEQ + qr) * HDIM + head * DHEAD + quad * 8;
    short8 bq0 = *(const short8*)qptr;
    short8 bq1 = *(const short8*)(qptr + 32);

    // staging: 16 chunks/tile (8 K + 8 V), 2 per wave
    const short* gp[2];
    int stp[2], ldo[2];
#pragma unroll
    for (int i = 0; i < 2; i++) {
        int c8 = w * 2 + i;
        if (c8 < 8) {
            int t = c8 >> 1, h = c8 & 1;
            gp[i] = Kbh + (size_t)(t * 16 + l15) * HDIM + h * 32 + quad * 8;
            stp[i] = 64 * HDIM;
        } else {
            int c = c8 - 8, dt = c >> 1, kh = c & 1;
            gp[i] = Vth + (size_t)(dt * 16 + l15) * SEQ + kh * 32 + quad * 8;
            stp[i] = 64;
        }
        ldo[i] = c8 * 512;
        gp[i] += (size_t)it0 * stp[i];               // start at tile it0
    }

    f32x4 o[4];
#pragma unroll
    for (int dt = 0; dt < 4; dt++) o[dt] = (f32x4){0.f, 0.f, 0.f, 0.f};
    float psum = 0.f;                    // per-lane partial sum of 2^s

    // prologue: stage tile it0 into buffer 0
#pragma unroll
    for (int i = 0; i < 2; i++) { gload16(gp[i], &SMEM[ldo[i]]); gp[i] += stp[i]; }

    for (int j = 0; j < nj; ++j) {
        const int cur = j & 1;
        short* Ks = &SMEM[cur * 8192];
        short* Vs = Ks + 4096;

        if (j + 1 < nj) {                // prefetch next tile into other buf
            short* nb = &SMEM[(cur ^ 1) * 8192];
#pragma unroll
            for (int i = 0; i < 2; i++) { gload16(gp[i], nb + ldo[i]); gp[i] += stp[i]; }
            asm volatile("s_waitcnt vmcnt(2)" ::: "memory");   // tile(j) landed
        } else {
            asm volatile("s_waitcnt vmcnt(0)" ::: "memory");
        }
        __builtin_amdgcn_s_barrier();    // tile j visible; prev reads done

        const int itg = it0 + j;
        const int s0 = itg * 64;
        f32x4 sv[4];
        __builtin_amdgcn_s_setprio(1);
#pragma unroll
        for (int t = 0; t < 4; t++) {
            sv[t] = (f32x4){0.f, 0.f, 0.f, 0.f};
            short8 k0 = *(const short8*)&Ks[(t * 2) * 512 + lane * 8];
            short8 k1 = *(const short8*)&Ks[(t * 2 + 1) * 512 + lane * 8];
            sv[t] = __builtin_amdgcn_mfma_f32_16x16x32_bf16(k0, bq0, sv[t], 0, 0, 0);
            sv[t] = __builtin_amdgcn_mfma_f32_16x16x32_bf16(k1, bq1, sv[t], 0, 0, 0);
        }
        __builtin_amdgcn_s_setprio(0);

        float p[16];
        if (itg >= s_w) {                // diagonal or beyond for this wave
#pragma unroll
            for (int t = 0; t < 4; t++)
#pragma unroll
                for (int r = 0; r < 4; r++) {
                    int key = s0 + t * 16 + quad * 4 + r;
                    p[t * 4 + r] = (key <= qr) ? EXP2F(sv[t][r]) : 0.f;
                }
        } else {
#pragma unroll
            for (int t = 0; t < 4; t++)
#pragma unroll
                for (int r = 0; r < 4; r++)
                    p[t * 4 + r] = EXP2F(sv[t][r]);
        }
#pragma unroll
        for (int i = 0; i < 16; i++) psum += p[i];

#pragma unroll
        for (int t = 0; t < 4; t++) {
            uint2 u2;
            u2.x = pk2(p[t * 4],     p[t * 4 + 1]);
            u2.y = pk2(p[t * 4 + 2], p[t * 4 + 3]);
            *(uint2*)&Pw[l15 * 72 + t * 16 + quad * 4] = u2;
        }
        short8 bp0 = *(const short8*)&Pw[l15 * 72 + quad * 8];
        short8 bp1 = *(const short8*)&Pw[l15 * 72 + 32 + quad * 8];

        __builtin_amdgcn_s_setprio(1);
#pragma unroll
        for (int dt = 0; dt < 4; dt++) {
            short8 av0 = *(const short8*)&Vs[(dt * 2) * 512 + lane * 8];
            short8 av1 = *(const short8*)&Vs[(dt * 2 + 1) * 512 + lane * 8];
            o[dt] = __builtin_amdgcn_mfma_f32_16x16x32_bf16(av0, bp0, o[dt], 0, 0, 0);
            o[dt] = __builtin_amdgcn_mfma_f32_16x16x32_bf16(av1, bp1, o[dt], 0, 0, 0);
        }
        __builtin_amdgcn_s_setprio(0);
        __builtin_amdgcn_s_barrier();    // reads of buf(cur) done before
                                         // next iter's prefetch overwrites
    }

    float lrow = psum + __shfl_xor(psum, 16);
    lrow += __shfl_xor(lrow, 32);

    if (half >= 0) {                     // split: f32 partials, no normalize
        const int tile = (pair * 8 + (sblk - 8)) * 2 + half;
        float* Ot = Opart + (size_t)tile * 8192;
#pragma unroll
        for (int dt = 0; dt < 4; dt++)
            *(f32x4*)&Ot[rho * 64 + dt * 16 + quad * 4] = o[dt];
        if (quad == 0) Psum[(pair * 8 + (sblk - 8)) * 256 + half * 128 + rho] = lrow;
        return;
    }

    const float inv = 1.f / lrow;
    const size_t obase = (size_t)(b * SEQ + qr) * HDIM + head * DHEAD;
#pragma unroll
    for (int dt = 0; dt < 4; dt++) {
        uint2 u2;
        u2.x = pk2(o[dt][0] * inv, o[dt][1] * inv);
        u2.y = pk2(o[dt][2] * inv, o[dt][3] * inv);
        *(uint2*)&Ab[obase + dt * 16 + quad * 4] = u2;
    }
}

// ---------------------------------------------------------------------------
// combine: for each split strip (pair x sblk 8..15 = 256), sum the halves'
// O-partials (128x64 f32 each) and row-sums, normalize, write bf16 into Ab.
// Runs after attn, before gemm_o (which overwrites d_out).
// ---------------------------------------------------------------------------
__global__ __launch_bounds__(256) void combine(const float* __restrict__ Opart,
        const float* __restrict__ Psum, short* __restrict__ Ab)
{
    const int bxx = blockIdx.x;          // 0..255
    const int pair = bxx & 31, si = bxx >> 5;     // si 0..7 -> sblk = 8+si
    const int b = pair >> 4, head = pair & 15;
    const int tid = threadIdx.x;
    const int row = tid >> 1, dq = (tid & 1) * 32;   // 2 threads/row, 32 cols

    const size_t t0 = ((size_t)(pair * 8 + si) * 2) * 8192;
    const float* O0 = Opart + t0;
    const float* O1 = O0 + 8192;
    const int p0 = (pair * 8 + si) * 256;
    const float inv = 1.f / (Psum[p0 + row] + Psum[p0 + 128 + row]);

    const int qrow = (8 + si) * 128 + row;
    const size_t obase = (size_t)(b * SEQ + qrow) * HDIM + head * DHEAD + dq;
#pragma unroll
    for (int g = 0; g < 8; g++) {
        float4 a = *(const float4*)&O0[row * 64 + dq + g * 4];
        float4 c = *(const float4*)&O1[row * 64 + dq + g * 4];
        ushort4 pk;
        pk.x = (unsigned short)f2bs((a.x + c.x) * inv);
        pk.y = (unsigned short)f2bs((a.y + c.y) * inv);
        pk.z = (unsigned short)f2bs((a.z + c.z) * inv);
        pk.w = (unsigned short)f2bs((a.w + c.w) * inv);
        *(ushort4*)&Ab[obase + g * 4] = pk;
    }
}

// ---------------------------------------------------------------------------
// O projection — 128x128, 8 waves, BK=64 counted-vmcnt dbuf (R14, passed).
// Frozen.
// ---------------------------------------------------------------------------
__global__ __launch_bounds__(512) void gemm_o(const short* __restrict__ A,
        const short* __restrict__ Bt, const float* __restrict__ bo,
        float* __restrict__ Out)
{
    __shared__ short SM[2 * 16384];  // [buf][As 8192 | Bs 8192] = 64 KB
    const int tid = threadIdx.x, lane = tid & 63, w = tid >> 6;   // 0..7
    const int quad = lane >> 4, l15 = lane & 15;
    const int m0 = blockIdx.y * 128, n0 = blockIdx.x * 128;
    const int wr = w >> 2, wc = w & 3;   // 2M x 4N

    const short* gsrc[4];
    short* ldst[4];
#pragma unroll
    for (int i = 0; i < 4; i++) {
        int c8 = w * 4 + i;
        if (c8 < 16) {
            gsrc[i] = A + (size_t)(m0 + (c8 >> 1) * 16 + l15) * HDIM
                        + (c8 & 1) * 32 + quad * 8;
            ldst[i] = &SM[c8 * 512];
        } else {
            int v = c8 - 16;
            gsrc[i] = Bt + (size_t)(n0 + (v >> 1) * 16 + l15) * HDIM
                         + (v & 1) * 32 + quad * 8;
            ldst[i] = &SM[8192 + v * 512];
        }
    }

    f32x4 acc[4][2];
#pragma unroll
    for (int i = 0; i < 4; i++)
#pragma unroll
        for (int j = 0; j < 2; j++) acc[i][j] = (f32x4){0.f, 0.f, 0.f, 0.f};

#pragma unroll
    for (int i = 0; i < 4; i++) { gload16(gsrc[i], ldst[i]); gsrc[i] += 64; }

    for (int kk = 0; kk < 16; ++kk) {
        const int cur = kk & 1;
        if (kk < 15) {
            const int nb = (cur ^ 1) * 16384;
#pragma unroll
            for (int i = 0; i < 4; i++) { gload16(gsrc[i], ldst[i] + nb); gsrc[i] += 64; }
            asm volatile("s_waitcnt vmcnt(4)" ::: "memory");   // tile(kk) landed
        } else {
            asm volatile("s_waitcnt vmcnt(0)" ::: "memory");
        }
        __builtin_amdgcn_s_barrier();

        const short* Asb = &SM[cur * 16384];
        const short* Bsb = Asb + 8192;
#pragma unroll
        for (int kh = 0; kh < 2; kh++) {
            short8 af[4], bfr[2];
#pragma unroll
            for (int mi = 0; mi < 4; mi++)
                af[mi] = *(const short8*)&Asb[((wr * 4 + mi) * 2 + kh) * 512 + lane * 8];
#pragma unroll
            for (int ni = 0; ni < 2; ni++)
                bfr[ni] = *(const short8*)&Bsb[((wc * 2 + ni) * 2 + kh) * 512 + lane * 8];
#pragma unroll
            for (int mi = 0; mi < 4; mi++)
#pragma unroll
                for (int ni = 0; ni < 2; ni++)
                    acc[mi][ni] = __builtin_amdgcn_mfma_f32_16x16x32_bf16(
                                      af[mi], bfr[ni], acc[mi][ni], 0, 0, 0);
        }
        __builtin_amdgcn_s_barrier();
    }

#pragma unroll
    for (int mi = 0; mi < 4; mi++) {
        int mB = m0 + (wr * 4 + mi) * 16 + quad * 4;
#pragma unroll
        for (int ni = 0; ni < 2; ni++) {
            int n = n0 + (wc * 2 + ni) * 16 + l15;
            float bb = bo[n];
#pragma unroll
            for (int r = 0; r < 4; r++)
                Out[(size_t)(mB + r) * HDIM + n] = acc[mi][ni][r] + bb;
        }
    }
}

// ---------------------------------------------------------------------------
extern "C" void kernel_launch(void* const* d_in, const int* in_sizes, int n_in,
                              void* d_out, int out_size, void* d_ws, size_t ws_size,
                              hipStream_t stream)
{
    const float* src = (const float*)d_in[0];
    const float* Wq = (const float*)d_in[2];
    const float* bq = (const float*)d_in[3];
    const float* Wk = (const float*)d_in[4];
    const float* bk = (const float*)d_in[5];
    const float* Wv = (const float*)d_in[6];
    const float* bv = (const float*)d_in[7];
    const float* Wo = (const float*)d_in[8];
    const float* bo = (const float*)d_in[9];
    float* out = (float*)d_out;

    // ws (34 MB): [Sb 8][Qb 8][Kb 8][Vt 8][WoT slot 2]
    // d_out scratch timeline: WT (qkv weights) -> attn O-partials -> out.
    // Sb scratch timeline: src bf16 (qkv input) -> attn psum partials.
    short* Sb   = (short*)d_ws;
    short* Qb   = Sb + (size_t)MROWS * HDIM;
    short* Kb   = Qb + (size_t)MROWS * HDIM;
    short* Vt   = Kb + (size_t)MROWS * HDIM;
    short* WoT  = Vt + (size_t)MROWS * HDIM;   // 2 MB slot
    short* WT   = (short*)d_out;               // 6 MB scratch in out buffer
    short* Ab   = Qb;                          // attention output over Q
    float* Opart = (float*)d_out;              // 16.78 MB: 512 x 128x64 f32
    float* Psum  = (float*)Sb;                 // 256 KB: 256 x 2 x 128 f32

    prep1<<<dim3(4096 + 1024), dim3(256), 0, stream>>>(src, Wq, Wk, Wv, Wo, Sb, WT, WoT);

    gemm_qkv<<<dim3(12, 16), dim3(512), 0, stream>>>(Sb, WT, bq, bk, bv, Qb, Kb, Vt);

    attn_mfma<<<dim3(768), dim3(512), 0, stream>>>(Qb, Kb, Vt, Ab, Opart, Psum);

    combine<<<dim3(256), dim3(256), 0, stream>>>(Opart, Psum, Ab);

    gemm_o<<<dim3(8, 32), dim3(512), 0, stream>>>(Ab, WoT, bo, out);
}

// Round 16
// 192.604 us; speedup vs baseline: 1.0618x; 1.0054x over previous
//
#include <hip/hip_runtime.h>
#include <hip/hip_bf16.h>

typedef __hip_bfloat16 bf16;
typedef __attribute__((ext_vector_type(8))) short short8;   // 8 bf16 = 4 VGPRs
typedef __attribute__((ext_vector_type(4))) float f32x4;

#define BATCH 2
#define SEQ   2048
#define HDIM  1024
#define NHEAD 16
#define DHEAD 64
#define MROWS (BATCH*SEQ)   // 4096

// scale folded into Q: (1/sqrt(64)) * log2(e)  -> softmax done in 2^x domain
#define QSCALE 0.18033688f
#define EXP2F(x) __builtin_amdgcn_exp2f(x)

static __device__ __forceinline__ short f2bs(float x) {
    __hip_bfloat16 h = (__hip_bfloat16)x;   // RNE convert
    return *reinterpret_cast<short*>(&h);
}
static __device__ __forceinline__ unsigned int pk2(float a, float b) {
    __hip_bfloat162 h = __float22bfloat162_rn(make_float2(a, b));
    return *reinterpret_cast<unsigned int*>(&h);   // v_cvt_pk; low short = a
}

// async global->LDS, 16B per lane; lane l lands at base + l*16.
static __device__ __forceinline__ void gload16(const void* g, void* l) {
    __builtin_amdgcn_global_load_lds(
        (const __attribute__((address_space(1))) unsigned int*)g,
        (__attribute__((address_space(3))) unsigned int*)l, 16, 0, 0);
}

// ---------------------------------------------------------------------------
// prep1: blocks 0..4095 convert src fp32->bf16 into Sb; blocks 4096..5119
// transpose all four weights: Wq,Wk,Wv into WT rows wsel*1024+n (WT lives in
// d_out scratch, dead until gemm_o overwrites it), Wo into WoT (slot).
// ---------------------------------------------------------------------------
__global__ __launch_bounds__(256) void prep1(const float* __restrict__ src,
        const float* __restrict__ Wq, const float* __restrict__ Wk,
        const float* __restrict__ Wv, const float* __restrict__ Wo,
        short* __restrict__ Sb, short* __restrict__ WT,
        short* __restrict__ WoT)
{
    __shared__ float t[64][65];
    const int bx = blockIdx.x, tid = threadIdx.x;
    if (bx < 4096) {                       // cvt: 4096*256 float4 = 4M elems
        int i = bx * 256 + tid;
        float4 v = ((const float4*)src)[i];
        ushort4 o;
        o.x = (unsigned short)f2bs(v.x);
        o.y = (unsigned short)f2bs(v.y);
        o.z = (unsigned short)f2bs(v.z);
        o.w = (unsigned short)f2bs(v.w);
        ((ushort4*)Sb)[i] = o;
        return;
    }
    const int tb = bx - 4096;              // [0, 1024)
    const int wsel = tb >> 8;              // 0=Wq 1=Wk 2=Wv 3=Wo
    const float* W = (wsel == 0) ? Wq : (wsel == 1) ? Wk : (wsel == 2) ? Wv : Wo;
    short* dst = (wsel < 3) ? WT : WoT;
    const int roff = (wsel < 3) ? wsel * 1024 : 0;
    const int t8 = tb & 255;
    const int n0 = (t8 & 15) * 64, k0 = (t8 >> 4) * 64;
#pragma unroll
    for (int i = 0; i < 16; i++) {
        int idx = tid + i * 256, r = idx >> 6, c = idx & 63;
        t[r][c] = W[(size_t)(k0 + r) * HDIM + n0 + c];
    }
    __syncthreads();
#pragma unroll
    for (int i = 0; i < 16; i++) {
        int idx = tid + i * 256, c = idx >> 6, r = idx & 63;
        dst[(size_t)(roff + n0 + c) * HDIM + k0 + r] = f2bs(t[r][c]);
    }
}

// ---------------------------------------------------------------------------
// Fused Q|K|V GEMM — 256(M) x 192(N), grid (16,16) = 256 blocks = every CU
// exactly once, WITH R12's counted-wait deep-issue structure (R13's failure
// was the vmcnt(0) drain it used, not the tile shape).
// Staging model: block stages 56 KB/K-tile x 16 = 896 KB; at the pinned
// ~21 KB/us/CU with ALL 256 CUs filled -> ~43 us (vs 48.2 at 192 CUs).
// Per-thread 7 loads/tile via static table CTAB: slots 0-5 hold all EARLY
// chunks (A 0..31 + B-frags 0-2 per wave-col: v in {0..5,12..17}); slot 6
// holds LATE (B-frags 3-5: v in {6..11,18..23}). Waits: vmcnt(1) at tile
// top (slots 0-5 of tile t in), single barrier, issue tile t+1 (depth kept),
// MFMA ni 0-2, vmcnt(7) (slot 6 in, t+1's 7 in flight), MFMA ni 3-5.
// WAR: buf(t+1) held tile t-1 whose MFMAs complete before the top barrier.
// Per-acc k-order unchanged -> bit-identical. Epilogue = R13's verified
// per-fragment region dispatch (rg = n>>10, fragment-uniform).
// ---------------------------------------------------------------------------
__global__ __launch_bounds__(512, 2) void gemm_qkv(const short* __restrict__ A,
        const short* __restrict__ Bt,
        const float* __restrict__ bq, const float* __restrict__ bk,
        const float* __restrict__ bv,
        short* __restrict__ Qout, short* __restrict__ Kout,
        short* __restrict__ Vtout)
{
    __shared__ short SM[2][28672];   // [buf][A 16384 | B 12288 shorts] = 112 KB
    const int tid = threadIdx.x, lane = tid & 63, w = tid >> 6;   // w 0..7
    const int quad = lane >> 4, l15 = lane & 15;
    const int m0 = blockIdx.y * 256, n0 = blockIdx.x * 192;
    const int wr = w >> 1, wc = w & 1;     // 4M x 2N wave grid

    // per-wave chunk table: entries <32 = A chunk, >=32 = B chunk (v = c-32).
    // slots 0-5 early, slot 6 late (see header).
    static const unsigned char CTAB[8][7] = {
        { 0,  1,  2,  3, 32 + 0,  32 + 1,  32 + 6 },
        { 4,  5,  6,  7, 32 + 2,  32 + 3,  32 + 7 },
        { 8,  9, 10, 11, 32 + 4,  32 + 5,  32 + 8 },
        {12, 13, 14, 15, 32 + 12, 32 + 13, 32 + 9 },
        {16, 17, 18, 19, 32 + 14, 32 + 10, 32 + 11},
        {20, 21, 22, 23, 32 + 15, 32 + 18, 32 + 19},
        {24, 25, 26, 27, 32 + 16, 32 + 20, 32 + 21},
        {28, 29, 30, 31, 32 + 17, 32 + 22, 32 + 23}
    };

    const short* gp[7];
    int lo[7];
#pragma unroll
    for (int i = 0; i < 7; i++) {
        int c = CTAB[w][i];
        if (c < 32) {
            gp[i] = A + (size_t)(m0 + (c >> 1) * 16 + l15) * HDIM
                      + (c & 1) * 32 + quad * 8;
            lo[i] = c * 512;
        } else {
            int v = c - 32;                          // 0..23
            gp[i] = Bt + (size_t)(n0 + (v >> 1) * 16 + l15) * HDIM
                       + (v & 1) * 32 + quad * 8;
            lo[i] = 16384 + v * 512;
        }
    }

    f32x4 acc[4][6];
#pragma unroll
    for (int i = 0; i < 4; i++)
#pragma unroll
        for (int j = 0; j < 6; j++) acc[i][j] = (f32x4){0.f, 0.f, 0.f, 0.f};

    // prologue: issue tile 0 into buf0 (slot order = wait order)
#pragma unroll
    for (int i = 0; i < 7; i++) { gload16(gp[i], &SM[0][lo[i]]); gp[i] += 64; }

    short8 af[4][2];
    for (int t = 0; t < 16; ++t) {
        const short* Tb = SM[t & 1];
        short* Sn = SM[(t + 1) & 1];

        asm volatile("s_waitcnt vmcnt(1)" ::: "memory");  // tile t slots 0-5 in
        __builtin_amdgcn_s_barrier();                     // publish tile t

        // ds_reads: all A frags + B n-frags 0..2 (early chunks)
#pragma unroll
        for (int mi = 0; mi < 4; mi++)
#pragma unroll
            for (int kh = 0; kh < 2; kh++)
                af[mi][kh] = *(const short8*)
                    &Tb[((wr * 4 + mi) * 2 + kh) * 512 + lane * 8];
        short8 bf01[3][2];
#pragma unroll
        for (int nn = 0; nn < 3; nn++)
#pragma unroll
            for (int kh = 0; kh < 2; kh++)
                bf01[nn][kh] = *(const short8*)
                    &Tb[16384 + ((wc * 6 + nn) * 2 + kh) * 512 + lane * 8];

        if (t < 15) {                    // deep-issue: all of tile t+1 now
#pragma unroll
            for (int i = 0; i < 7; i++) { gload16(gp[i], Sn + lo[i]); gp[i] += 64; }
        }

        __builtin_amdgcn_s_setprio(1);
#pragma unroll
        for (int nn = 0; nn < 3; nn++)
#pragma unroll
            for (int mi = 0; mi < 4; mi++)
#pragma unroll
                for (int kh = 0; kh < 2; kh++)
                    acc[mi][nn] = __builtin_amdgcn_mfma_f32_16x16x32_bf16(
                        af[mi][kh], bf01[nn][kh], acc[mi][nn], 0, 0, 0);
        __builtin_amdgcn_s_setprio(0);

        if (t < 15) asm volatile("s_waitcnt vmcnt(7)" ::: "memory");  // slot 6 in
        else        asm volatile("s_waitcnt vmcnt(0)" ::: "memory");

        short8 bf23[3][2];
#pragma unroll
        for (int nn = 0; nn < 3; nn++)
#pragma unroll
            for (int kh = 0; kh < 2; kh++)
                bf23[nn][kh] = *(const short8*)
                    &Tb[16384 + ((wc * 6 + 3 + nn) * 2 + kh) * 512 + lane * 8];

        __builtin_amdgcn_s_setprio(1);
#pragma unroll
        for (int nn = 0; nn < 3; nn++)
#pragma unroll
            for (int mi = 0; mi < 4; mi++)
#pragma unroll
                for (int kh = 0; kh < 2; kh++)
                    acc[mi][3 + nn] = __builtin_amdgcn_mfma_f32_16x16x32_bf16(
                        af[mi][kh], bf23[nn][kh], acc[mi][3 + nn], 0, 0, 0);
        __builtin_amdgcn_s_setprio(0);
    }

    // epilogue: region per n-fragment (tiles straddle Q|K|V boundaries)
#pragma unroll
    for (int mi = 0; mi < 4; mi++) {
        int mB = m0 + wr * 64 + mi * 16 + quad * 4;
        int bb = mB >> 11, tt = mB & 2047;
#pragma unroll
        for (int ni = 0; ni < 6; ni++) {
            int n = n0 + wc * 96 + ni * 16 + l15;
            int rg = n >> 10, nl = n & 1023;
            if (rg == 0) {
                float bbv = bq[nl];
#pragma unroll
                for (int r = 0; r < 4; r++)
                    Qout[(size_t)(mB + r) * HDIM + nl] =
                        f2bs((acc[mi][ni][r] + bbv) * QSCALE);
            } else if (rg == 1) {
                float bbv = bk[nl];
#pragma unroll
                for (int r = 0; r < 4; r++)
                    Kout[(size_t)(mB + r) * HDIM + nl] =
                        f2bs(acc[mi][ni][r] + bbv);
            } else {                                 // V: transposed store
                float bvv = bv[nl];
                int h = nl >> 6, d = nl & 63;
                size_t base = ((size_t)((bb * NHEAD + h) * DHEAD + d)) * SEQ + tt;
                ushort4 pk;
                pk.x = (unsigned short)f2bs(acc[mi][ni][0] + bvv);
                pk.y = (unsigned short)f2bs(acc[mi][ni][1] + bvv);
                pk.z = (unsigned short)f2bs(acc[mi][ni][2] + bvv);
                pk.w = (unsigned short)f2bs(acc[mi][ni][3] + bvv);
                *(ushort4*)(Vtout + base) = pk;
            }
        }
    }
}

// ---------------------------------------------------------------------------
// MFMA causal flash attention — 128 Q-rows/block shared staging + split long
// strips (R15, passed at 193.6 total). Frozen.
// ---------------------------------------------------------------------------
__global__ __launch_bounds__(512) void attn_mfma(const short* __restrict__ Qb,
        const short* __restrict__ Kb, const short* __restrict__ Vt,
        short* __restrict__ Ab,
        float* __restrict__ Opart, float* __restrict__ Psum)
{
    __shared__ short SMEM[25600];        // [2][8192] K|V dbuf | Ps 8x1152
    const int tid = threadIdx.x, lane = tid & 63, w = tid >> 6;   // w 0..7
    const int quad = lane >> 4, l15 = lane & 15;
    const int L = blockIdx.x;

    // unit table sorted by descending iteration count (heavy first)
    static const signed char S_TAB[24] =
        {15,15, 7,14,14,13,13, 6,12,12,11,11, 5,10,10, 9, 9, 4, 8, 8, 3, 2, 1, 0};
    static const signed char H_TAB[24] =
        { 0, 1,-1, 0, 1, 0, 1,-1, 0, 1, 0, 1,-1, 0, 1, 0, 1,-1, 0, 1,-1,-1,-1,-1};

    const int pair = (L & 7) + 8 * ((L >> 3) & 3);   // 0..31 (XCD affinity)
    const int u = L >> 5;                            // 0..23
    const int b = pair >> 4, head = pair & 15;
    const int sblk = S_TAB[u];
    const int half = H_TAB[u];                       // -1 unsplit, 0/1 halves
    const int it0   = (half == 1) ? (sblk + 1) : 0;
    const int itEnd = (half == 0) ? (sblk + 1) : (2 * sblk + 2);
    const int nj = itEnd - it0;

    const short* Kbh = Kb + (size_t)b * SEQ * HDIM + head * DHEAD;
    const short* Vth = Vt + (size_t)(b * NHEAD + head) * DHEAD * SEQ;
    short* Pw = SMEM + 16384 + w * 1152;

    const int s_w = 2 * sblk + (w >> 2);             // this wave's 64-strip
    const int rho = w * 16 + l15;                    // row within block 0..127
    const int qr = sblk * 128 + rho;                 // this lane's q-row

    const short* qptr = Qb + (size_t)(b * SEQ + qr) * HDIM + head * DHEAD + quad * 8;
    short8 bq0 = *(const short8*)qptr;
    short8 bq1 = *(const short8*)(qptr + 32);

    // staging: 16 chunks/tile (8 K + 8 V), 2 per wave
    const short* gp[2];
    int stp[2], ldo[2];
#pragma unroll
    for (int i = 0; i < 2; i++) {
        int c8 = w * 2 + i;
        if (c8 < 8) {
            int t = c8 >> 1, h = c8 & 1;
            gp[i] = Kbh + (size_t)(t * 16 + l15) * HDIM + h * 32 + quad * 8;
            stp[i] = 64 * HDIM;
        } else {
            int c = c8 - 8, dt = c >> 1, kh = c & 1;
            gp[i] = Vth + (size_t)(dt * 16 + l15) * SEQ + kh * 32 + quad * 8;
            stp[i] = 64;
        }
        ldo[i] = c8 * 512;
        gp[i] += (size_t)it0 * stp[i];               // start at tile it0
    }

    f32x4 o[4];
#pragma unroll
    for (int dt = 0; dt < 4; dt++) o[dt] = (f32x4){0.f, 0.f, 0.f, 0.f};
    float psum = 0.f;                    // per-lane partial sum of 2^s

    // prologue: stage tile it0 into buffer 0
#pragma unroll
    for (int i = 0; i < 2; i++) { gload16(gp[i], &SMEM[ldo[i]]); gp[i] += stp[i]; }

    for (int j = 0; j < nj; ++j) {
        const int cur = j & 1;
        short* Ks = &SMEM[cur * 8192];
        short* Vs = Ks + 4096;

        if (j + 1 < nj) {                // prefetch next tile into other buf
            short* nb = &SMEM[(cur ^ 1) * 8192];
#pragma unroll
            for (int i = 0; i < 2; i++) { gload16(gp[i], nb + ldo[i]); gp[i] += stp[i]; }
            asm volatile("s_waitcnt vmcnt(2)" ::: "memory");   // tile(j) landed
        } else {
            asm volatile("s_waitcnt vmcnt(0)" ::: "memory");
        }
        __builtin_amdgcn_s_barrier();    // tile j visible; prev reads done

        const int itg = it0 + j;
        const int s0 = itg * 64;
        f32x4 sv[4];
        __builtin_amdgcn_s_setprio(1);
#pragma unroll
        for (int t = 0; t < 4; t++) {
            sv[t] = (f32x4){0.f, 0.f, 0.f, 0.f};
            short8 k0 = *(const short8*)&Ks[(t * 2) * 512 + lane * 8];
            short8 k1 = *(const short8*)&Ks[(t * 2 + 1) * 512 + lane * 8];
            sv[t] = __builtin_amdgcn_mfma_f32_16x16x32_bf16(k0, bq0, sv[t], 0, 0, 0);
            sv[t] = __builtin_amdgcn_mfma_f32_16x16x32_bf16(k1, bq1, sv[t], 0, 0, 0);
        }
        __builtin_amdgcn_s_setprio(0);

        float p[16];
        if (itg >= s_w) {                // diagonal or beyond for this wave
#pragma unroll
            for (int t = 0; t < 4; t++)
#pragma unroll
                for (int r = 0; r < 4; r++) {
                    int key = s0 + t * 16 + quad * 4 + r;
                    p[t * 4 + r] = (key <= qr) ? EXP2F(sv[t][r]) : 0.f;
                }
        } else {
#pragma unroll
            for (int t = 0; t < 4; t++)
#pragma unroll
                for (int r = 0; r < 4; r++)
                    p[t * 4 + r] = EXP2F(sv[t][r]);
        }
#pragma unroll
        for (int i = 0; i < 16; i++) psum += p[i];

#pragma unroll
        for (int t = 0; t < 4; t++) {
            uint2 u2;
            u2.x = pk2(p[t * 4],     p[t * 4 + 1]);
            u2.y = pk2(p[t * 4 + 2], p[t * 4 + 3]);
            *(uint2*)&Pw[l15 * 72 + t * 16 + quad * 4] = u2;
        }
        short8 bp0 = *(const short8*)&Pw[l15 * 72 + quad * 8];
        short8 bp1 = *(const short8*)&Pw[l15 * 72 + 32 + quad * 8];

        __builtin_amdgcn_s_setprio(1);
#pragma unroll
        for (int dt = 0; dt < 4; dt++) {
            short8 av0 = *(const short8*)&Vs[(dt * 2) * 512 + lane * 8];
            short8 av1 = *(const short8*)&Vs[(dt * 2 + 1) * 512 + lane * 8];
            o[dt] = __builtin_amdgcn_mfma_f32_16x16x32_bf16(av0, bp0, o[dt], 0, 0, 0);
            o[dt] = __builtin_amdgcn_mfma_f32_16x16x32_bf16(av1, bp1, o[dt], 0, 0, 0);
        }
        __builtin_amdgcn_s_setprio(0);
        __builtin_amdgcn_s_barrier();    // reads of buf(cur) done before
                                         // next iter's prefetch overwrites
    }

    float lrow = psum + __shfl_xor(psum, 16);
    lrow += __shfl_xor(lrow, 32);

    if (half >= 0) {                     // split: f32 partials, no normalize
        const int tile = (pair * 8 + (sblk - 8)) * 2 + half;
        float* Ot = Opart + (size_t)tile * 8192;
#pragma unroll
        for (int dt = 0; dt < 4; dt++)
            *(f32x4*)&Ot[rho * 64 + dt * 16 + quad * 4] = o[dt];
        if (quad == 0) Psum[(pair * 8 + (sblk - 8)) * 256 + half * 128 + rho] = lrow;
        return;
    }

    const float inv = 1.f / lrow;
    const size_t obase = (size_t)(b * SEQ + qr) * HDIM + head * DHEAD;
#pragma unroll
    for (int dt = 0; dt < 4; dt++) {
        uint2 u2;
        u2.x = pk2(o[dt][0] * inv, o[dt][1] * inv);
        u2.y = pk2(o[dt][2] * inv, o[dt][3] * inv);
        *(uint2*)&Ab[obase + dt * 16 + quad * 4] = u2;
    }
}

// ---------------------------------------------------------------------------
// combine: for each split strip (pair x sblk 8..15 = 256), sum the halves'
// O-partials (128x64 f32 each) and row-sums, normalize, write bf16 into Ab.
// (R15, passed.) Frozen.
// ---------------------------------------------------------------------------
__global__ __launch_bounds__(256) void combine(const float* __restrict__ Opart,
        const float* __restrict__ Psum, short* __restrict__ Ab)
{
    const int bxx = blockIdx.x;          // 0..255
    const int pair = bxx & 31, si = bxx >> 5;     // si 0..7 -> sblk = 8+si
    const int b = pair >> 4, head = pair & 15;
    const int tid = threadIdx.x;
    const int row = tid >> 1, dq = (tid & 1) * 32;   // 2 threads/row, 32 cols

    const size_t t0 = ((size_t)(pair * 8 + si) * 2) * 8192;
    const float* O0 = Opart + t0;
    const float* O1 = O0 + 8192;
    const int p0 = (pair * 8 + si) * 256;
    const float inv = 1.f / (Psum[p0 + row] + Psum[p0 + 128 + row]);

    const int qrow = (8 + si) * 128 + row;
    const size_t obase = (size_t)(b * SEQ + qrow) * HDIM + head * DHEAD + dq;
#pragma unroll
    for (int g = 0; g < 8; g++) {
        float4 a = *(const float4*)&O0[row * 64 + dq + g * 4];
        float4 c = *(const float4*)&O1[row * 64 + dq + g * 4];
        ushort4 pk;
        pk.x = (unsigned short)f2bs((a.x + c.x) * inv);
        pk.y = (unsigned short)f2bs((a.y + c.y) * inv);
        pk.z = (unsigned short)f2bs((a.z + c.z) * inv);
        pk.w = (unsigned short)f2bs((a.w + c.w) * inv);
        *(ushort4*)&Ab[obase + g * 4] = pk;
    }
}

// ---------------------------------------------------------------------------
// O projection — 128x128, 8 waves, BK=64 counted-vmcnt dbuf (R15, passed).
// Frozen.
// ---------------------------------------------------------------------------
__global__ __launch_bounds__(512) void gemm_o(const short* __restrict__ A,
        const short* __restrict__ Bt, const float* __restrict__ bo,
        float* __restrict__ Out)
{
    __shared__ short SM[2 * 16384];  // [buf][As 8192 | Bs 8192] = 64 KB
    const int tid = threadIdx.x, lane = tid & 63, w = tid >> 6;   // 0..7
    const int quad = lane >> 4, l15 = lane & 15;
    const int m0 = blockIdx.y * 128, n0 = blockIdx.x * 128;
    const int wr = w >> 2, wc = w & 3;   // 2M x 4N

    const short* gsrc[4];
    short* ldst[4];
#pragma unroll
    for (int i = 0; i < 4; i++) {
        int c8 = w * 4 + i;
        if (c8 < 16) {
            gsrc[i] = A + (size_t)(m0 + (c8 >> 1) * 16 + l15) * HDIM
                        + (c8 & 1) * 32 + quad * 8;
            ldst[i] = &SM[c8 * 512];
        } else {
            int v = c8 - 16;
            gsrc[i] = Bt + (size_t)(n0 + (v >> 1) * 16 + l15) * HDIM
                         + (v & 1) * 32 + quad * 8;
            ldst[i] = &SM[8192 + v * 512];
        }
    }

    f32x4 acc[4][2];
#pragma unroll
    for (int i = 0; i < 4; i++)
#pragma unroll
        for (int j = 0; j < 2; j++) acc[i][j] = (f32x4){0.f, 0.f, 0.f, 0.f};

#pragma unroll
    for (int i = 0; i < 4; i++) { gload16(gsrc[i], ldst[i]); gsrc[i] += 64; }

    for (int kk = 0; kk < 16; ++kk) {
        const int cur = kk & 1;
        if (kk < 15) {
            const int nb = (cur ^ 1) * 16384;
#pragma unroll
            for (int i = 0; i < 4; i++) { gload16(gsrc[i], ldst[i] + nb); gsrc[i] += 64; }
            asm volatile("s_waitcnt vmcnt(4)" ::: "memory");   // tile(kk) landed
        } else {
            asm volatile("s_waitcnt vmcnt(0)" ::: "memory");
        }
        __builtin_amdgcn_s_barrier();

        const short* Asb = &SM[cur * 16384];
        const short* Bsb = Asb + 8192;
#pragma unroll
        for (int kh = 0; kh < 2; kh++) {
            short8 af[4], bfr[2];
#pragma unroll
            for (int mi = 0; mi < 4; mi++)
                af[mi] = *(const short8*)&Asb[((wr * 4 + mi) * 2 + kh) * 512 + lane * 8];
#pragma unroll
            for (int ni = 0; ni < 2; ni++)
                bfr[ni] = *(const short8*)&Bsb[((wc * 2 + ni) * 2 + kh) * 512 + lane * 8];
#pragma unroll
            for (int mi = 0; mi < 4; mi++)
#pragma unroll
                for (int ni = 0; ni < 2; ni++)
                    acc[mi][ni] = __builtin_amdgcn_mfma_f32_16x16x32_bf16(
                                      af[mi], bfr[ni], acc[mi][ni], 0, 0, 0);
        }
        __builtin_amdgcn_s_barrier();
    }

#pragma unroll
    for (int mi = 0; mi < 4; mi++) {
        int mB = m0 + (wr * 4 + mi) * 16 + quad * 4;
#pragma unroll
        for (int ni = 0; ni < 2; ni++) {
            int n = n0 + (wc * 2 + ni) * 16 + l15;
            float bb = bo[n];
#pragma unroll
            for (int r = 0; r < 4; r++)
                Out[(size_t)(mB + r) * HDIM + n] = acc[mi][ni][r] + bb;
        }
    }
}

// ---------------------------------------------------------------------------
extern "C" void kernel_launch(void* const* d_in, const int* in_sizes, int n_in,
                              void* d_out, int out_size, void* d_ws, size_t ws_size,
                              hipStream_t stream)
{
    const float* src = (const float*)d_in[0];
    const float* Wq = (const float*)d_in[2];
    const float* bq = (const float*)d_in[3];
    const float* Wk = (const float*)d_in[4];
    const float* bk = (const float*)d_in[5];
    const float* Wv = (const float*)d_in[6];
    const float* bv = (const float*)d_in[7];
    const float* Wo = (const float*)d_in[8];
    const float* bo = (const float*)d_in[9];
    float* out = (float*)d_out;

    // ws (34 MB): [Sb 8][Qb 8][Kb 8][Vt 8][WoT slot 2]
    // d_out scratch timeline: WT (qkv weights) -> attn O-partials -> out.
    // Sb scratch timeline: src bf16 (qkv input) -> attn psum partials.
    short* Sb   = (short*)d_ws;
    short* Qb   = Sb + (size_t)MROWS * HDIM;
    short* Kb   = Qb + (size_t)MROWS * HDIM;
    short* Vt   = Kb + (size_t)MROWS * HDIM;
    short* WoT  = Vt + (size_t)MROWS * HDIM;   // 2 MB slot
    short* WT   = (short*)d_out;               // 6 MB scratch in out buffer
    short* Ab   = Qb;                          // attention output over Q
    float* Opart = (float*)d_out;              // 16.78 MB: 512 x 128x64 f32
    float* Psum  = (float*)Sb;                 // 256 KB: 256 x 2 x 128 f32

    prep1<<<dim3(4096 + 1024), dim3(256), 0, stream>>>(src, Wq, Wk, Wv, Wo, Sb, WT, WoT);

    gemm_qkv<<<dim3(16, 16), dim3(512), 0, stream>>>(Sb, WT, bq, bk, bv, Qb, Kb, Vt);

    attn_mfma<<<dim3(768), dim3(512), 0, stream>>>(Qb, Kb, Vt, Ab, Opart, Psum);

    combine<<<dim3(256), dim3(256), 0, stream>>>(Opart, Psum, Ab);

    gemm_o<<<dim3(8, 32), dim3(512), 0, stream>>>(Ab, WoT, bo, out);
}